// Round 3
// baseline (1045.318 us; speedup 1.0000x reference)
//
#include <hip/hip_runtime.h>
#include <math.h>

// ---------------- workspace layout (floats) ----------------
#define OFF_Y2   0
#define OFF_QKV  17981440
#define OFF_LOGO (17981440 + 1990656)
#define OFF_ST   (17981440 + 5971968)
// stats offsets
#define ST_SX   0
#define ST_SXX  22
#define ST_WF   506
#define ST_BF   990
#define ST_Y2S  1012
#define ST_Y2Q  1032
#define ST_TOT  1052

#define LOGEPS -9.210340371976182f
#define NSWEEP 5

// ---------------- K0: zero stats ----------------
__global__ __launch_bounds__(256) void k0_zero(float* __restrict__ st){
  for (int i = threadIdx.x; i < ST_TOT; i += 256) st[i] = 0.f;
}

// ---------------- K1: x second moments (for closed-form BN1 stats) ----------------
__global__ __launch_bounds__(256) void k1_xstats(const float* __restrict__ x, float* __restrict__ st){
  __shared__ __align__(16) float xs[22*444];
  const float* xb = x + (size_t)blockIdx.x * (22*438);
  for (int i = threadIdx.x; i < 22*444; i += 256){
    int h = i / 444, w = i - h*444;
    xs[i] = (w < 438) ? xb[h*438 + w] : 0.f;
  }
  __syncthreads();
  for (int t = threadIdx.x; t < 275; t += 256){
    if (t < 22){
      const float4* r = (const float4*)&xs[t*444];
      float4 acc = {0.f,0.f,0.f,0.f};
      for (int w = 0; w < 111; ++w){ float4 v = r[w]; acc.x+=v.x; acc.y+=v.y; acc.z+=v.z; acc.w+=v.w; }
      atomicAdd(&st[ST_SX + t], acc.x+acc.y+acc.z+acc.w);
    } else {
      int rem = t - 22, h = 0;
      while (rem >= 22 - h){ rem -= 22 - h; ++h; }
      int h2 = h + rem;
      const float4* ra = (const float4*)&xs[h*444];
      const float4* rb = (const float4*)&xs[h2*444];
      float4 acc = {0.f,0.f,0.f,0.f};
      for (int w = 0; w < 111; ++w){
        float4 a = ra[w], b = rb[w];
        acc.x = fmaf(a.x,b.x,acc.x); acc.y = fmaf(a.y,b.y,acc.y);
        acc.z = fmaf(a.z,b.z,acc.z); acc.w = fmaf(a.w,b.w,acc.w);
      }
      atomicAdd(&st[ST_SXX + h*22 + h2], acc.x+acc.y+acc.z+acc.w);
    }
  }
}

// ---------------- K1b: fold BN1 into conv1 weights ----------------
__global__ __launch_bounds__(64) void k1b_fold(const float* __restrict__ W1, const float* __restrict__ g1,
                                               const float* __restrict__ be1, float* __restrict__ st){
  int c = threadIdx.x;
  if (c >= 22) return;
  const float invN = 1.f / (2048.f*438.f);
  float mcol[22];
  float mu0 = 0.f;
  for (int h = 0; h < 22; ++h){ mcol[h] = W1[c*22 + h]; mu0 = fmaf(mcol[h], st[ST_SX + h], mu0); }
  mu0 *= invN;
  float qf = 0.f;
  for (int h = 0; h < 22; ++h)
    for (int h2 = h; h2 < 22; ++h2){
      float w = mcol[h]*mcol[h2]*st[ST_SXX + h*22 + h2];
      qf += (h2 == h) ? w : 2.f*w;
    }
  qf *= invN;
  float var = qf - mu0*mu0;
  float a1 = g1[c] * rsqrtf(var + 1e-5f);
  for (int h = 0; h < 22; ++h) st[ST_WF + h*22 + c] = a1 * mcol[h];
  st[ST_BF + c] = be1[c] - a1 * mu0;   // b1 cancels exactly
}

// ---------------- K3: fused conv1+BN1+conv2 (24-wide output tiles: DS-traffic bound fix) ----
__global__ __launch_bounds__(512) void k3_conv(const float* __restrict__ x, const float* __restrict__ W2,
                                               const float* __restrict__ st, float* __restrict__ y2){
  __shared__ __align__(16) float zs[22*452 + 20];  // +20: OOB-read slack for 36-float windows
  __shared__ __align__(16) float w2s[20*268];
  __shared__ __align__(16) float wfs[22*24];
  __shared__ float bfs[22];
  int tid = threadIdx.x;
  int n = blockIdx.x;
  for (int i = tid; i < 484; i += 512){ int h = i/22, c = i - h*22; wfs[h*24 + c] = st[ST_WF + i]; }
  for (int i = tid; i < 5280; i += 512){ int d = i/264, r = i - d*264; w2s[d*268 + r] = W2[i]; }
  if (tid < 22) bfs[tid] = st[ST_BF + tid];
  for (int i = tid; i < 22*14; i += 512){ int c = i/14, k = i - c*14; int w = (k < 6) ? k : (438 + k); zs[c*452 + w] = 0.f; }
  __syncthreads();
  if (tid < 438){
    float acc[22];
    #pragma unroll
    for (int c = 0; c < 22; ++c) acc[c] = bfs[c];
    const float* xb = x + (size_t)n*(22*438) + tid;
    #pragma unroll 1
    for (int h = 0; h < 22; ++h){
      float xv = xb[h*438];
      #pragma unroll
      for (int c = 0; c < 22; ++c) acc[c] = fmaf(wfs[h*24 + c], xv, acc[c]);
    }
    #pragma unroll
    for (int c = 0; c < 22; ++c) zs[c*452 + tid + 6] = acc[c];
  }
  __syncthreads();
  // conv2: one 24-wide tile per thread: 380 items = 20 d x 19 chunks
  if (tid < 380){
    int d = tid / 19, chunk = tid - d*19;
    int w0 = chunk*24;
    float acc[24];
    #pragma unroll
    for (int jj = 0; jj < 24; ++jj) acc[jj] = 0.f;
    #pragma unroll 1
    for (int c = 0; c < 22; ++c){
      const float* zr = &zs[c*452 + w0];
      float zw[36];
      #pragma unroll
      for (int k = 0; k < 36; k += 4){ float4 v = *(const float4*)&zr[k]; zw[k]=v.x; zw[k+1]=v.y; zw[k+2]=v.z; zw[k+3]=v.w; }
      const float* wr = &w2s[d*268 + c*12];
      float wt[12];
      #pragma unroll
      for (int t = 0; t < 12; t += 4){ float4 v = *(const float4*)&wr[t]; wt[t]=v.x; wt[t+1]=v.y; wt[t+2]=v.z; wt[t+3]=v.w; }
      #pragma unroll
      for (int jj = 0; jj < 24; ++jj)
        #pragma unroll
        for (int t = 0; t < 12; ++t)
          acc[jj] = fmaf(wt[t], zw[jj+t], acc[jj]);
    }
    float* yb = y2 + (size_t)n*8780 + d*439;
    #pragma unroll
    for (int jj = 0; jj < 24; ++jj){ int w = w0 + jj; if (w < 439) yb[w] = acc[jj]; }
  }
}

// ---------------- K3b: y2 per-channel sum/sumsq ----------------
__global__ __launch_bounds__(256) void k3b_y2stats(const float* __restrict__ y2, float* __restrict__ st){
  int d = blockIdx.x, chunk = blockIdx.y;
  float sum = 0.f, sq = 0.f;
  for (int n = chunk*128; n < chunk*128 + 128; ++n){
    const float* r = y2 + (size_t)n*8780 + d*439;
    for (int w = threadIdx.x; w < 439; w += 256){ float v = r[w]; sum += v; sq = fmaf(v, v, sq); }
  }
  __shared__ float red[4][2];
  for (int off = 32; off; off >>= 1){ sum += __shfl_down(sum, off); sq += __shfl_down(sq, off); }
  int wid = threadIdx.x >> 6;
  if ((threadIdx.x & 63) == 0){ red[wid][0] = sum; red[wid][1] = sq; }
  __syncthreads();
  if (threadIdx.x == 0){
    float s = 0.f, q = 0.f;
    for (int i = 0; i < 4; ++i){ s += red[i][0]; q += red[i][1]; }
    atomicAdd(&st[ST_Y2S + d], s);
    atomicAdd(&st[ST_Y2Q + d], q);
  }
}

// ---------------- K4: covariance + Q/K/V congruence (patch-split LDS, float4 dots) ------
__global__ __launch_bounds__(256) void k4_cov_qkv(const float* __restrict__ y2, const float* __restrict__ st,
    const float* __restrict__ g2, const float* __restrict__ Wq, const float* __restrict__ Wk,
    const float* __restrict__ Wv, float* __restrict__ qkv){
  __shared__ __align__(16) float ysp[3][20][148];  // patch-split, zero-padded to 148
  __shared__ float a2s[20];
  __shared__ __align__(16) float Bt[3][18][20];    // [wt][i][d] = a2[d]*W[d][i]
  __shared__ __align__(16) float G3[3][400];
  __shared__ __align__(16) float Tmt[3][360];      // [m][jj*20+p]
  __shared__ float musum3[3][20];
  __shared__ float rtr3[3];
  int tid = threadIdx.x, n = blockIdx.x;
  if (tid < 20){
    const float invN = 1.f/(2048.f*439.f);
    float s = st[ST_Y2S + tid]*invN;
    float q = st[ST_Y2Q + tid]*invN;
    a2s[tid] = g2[tid] * rsqrtf(q - s*s + 1e-5f);
  }
  const float* yb = y2 + (size_t)n*8780;
  for (int i = tid; i < 8780; i += 256){
    int d = i/439, w = i - d*439;
    int m = (w >= 293) ? 2 : ((w >= 147) ? 1 : 0);
    int lw = w - ((m == 2) ? 293 : ((m == 1) ? 147 : 0));
    ysp[m][d][lw] = yb[i];
  }
  if (tid < 100){   // zero the pad slots
    int d = tid/5, k = tid - d*5;
    int m = (k == 0) ? 0 : ((k < 3) ? 1 : 2);
    int lw = (k == 0) ? 147 : ((k == 1 || k == 3) ? 146 : 147);
    ysp[m][d][lw] = 0.f;
  }
  __syncthreads();
  // Bt (1080) + musum (60)
  for (int i = tid; i < 1140; i += 256){
    if (i < 1080){
      int wt = i/360, r = i - wt*360; int d = r/18, jj = r - d*18;
      const float* Wm = (wt==0) ? Wq : ((wt==1) ? Wk : Wv);
      Bt[wt][jj][d] = a2s[d]*Wm[d*18 + jj];
    } else {
      int t = i - 1080; int m = t/20, d = t - m*20;
      const float4* r = (const float4*)&ysp[m][d][0];
      float4 acc = {0.f,0.f,0.f,0.f};
      #pragma unroll 1
      for (int w = 0; w < 37; ++w){ float4 v = r[w]; acc.x+=v.x; acc.y+=v.y; acc.z+=v.z; acc.w+=v.w; }
      musum3[m][d] = acc.x+acc.y+acc.z+acc.w;
    }
  }
  __syncthreads();
  // covariance pairs: 630 items (3 patches x 210 pairs), float4 dots
  for (int it = tid; it < 630; it += 256){
    int m = it/210, t = it - m*210;
    int rem = t, c = 0;
    while (rem >= 20 - c){ rem -= 20 - c; ++c; }
    int d = c + rem;
    const float4* ra = (const float4*)&ysp[m][c][0];
    const float4* rb = (const float4*)&ysp[m][d][0];
    float4 acc4 = {0.f,0.f,0.f,0.f};
    #pragma unroll 1
    for (int w = 0; w < 37; ++w){
      float4 a = ra[w], b = rb[w];
      acc4.x = fmaf(a.x,b.x,acc4.x); acc4.y = fmaf(a.y,b.y,acc4.y);
      acc4.z = fmaf(a.z,b.z,acc4.z); acc4.w = fmaf(a.w,b.w,acc4.w);
    }
    float invL = (m == 0) ? (1.f/147.f) : (1.f/146.f);
    float acc = (acc4.x+acc4.y+acc4.z+acc4.w) - musum3[m][c]*musum3[m][d]*invL;
    G3[m][c*20 + d] = acc; G3[m][d*20 + c] = acc;
  }
  __syncthreads();
  for (int wt = 0; wt < 3; ++wt){
    // Tm pass (1080 items) + rtr (3, first wt only)
    for (int i = tid; i < 1083; i += 256){
      if (i < 1080){
        int m = i/360, r = i - m*360; int p = r/18, jj = r - p*18;
        const float4* gr = (const float4*)&G3[m][p*20];
        const float4* br = (const float4*)&Bt[wt][jj][0];
        float4 a4 = {0.f,0.f,0.f,0.f};
        #pragma unroll
        for (int w = 0; w < 5; ++w){
          float4 a = gr[w], b = br[w];
          a4.x = fmaf(a.x,b.x,a4.x); a4.y = fmaf(a.y,b.y,a4.y);
          a4.z = fmaf(a.z,b.z,a4.z); a4.w = fmaf(a.w,b.w,a4.w);
        }
        Tmt[m][jj*20 + p] = a4.x+a4.y+a4.z+a4.w;
      } else if (wt == 0){
        int m = i - 1080;
        float tr = 0.f;
        for (int c = 0; c < 20; ++c){ float a = a2s[c]; tr = fmaf(a*a, G3[m][c*21], tr); }
        rtr3[m] = 1.f/tr;
      }
    }
    __syncthreads();
    // final pass: 513 items (3 m x 171 triu)
    for (int it = tid; it < 513; it += 256){
      int m = it/171, t = it - m*171;
      int rem = t, i = 0;
      while (rem >= 18 - i){ rem -= 18 - i; ++i; }
      int jj = i + rem;
      const float4* br = (const float4*)&Bt[wt][i][0];
      const float4* tr = (const float4*)&Tmt[m][jj*20];
      float4 a4 = {0.f,0.f,0.f,0.f};
      #pragma unroll
      for (int w = 0; w < 5; ++w){
        float4 a = br[w], b = tr[w];
        a4.x = fmaf(a.x,b.x,a4.x); a4.y = fmaf(a.y,b.y,a4.y);
        a4.z = fmaf(a.z,b.z,a4.z); a4.w = fmaf(a.w,b.w,a4.w);
      }
      float acc = (a4.x+a4.y+a4.z+a4.w) * rtr3[m];
      if (i == jj) acc += 1e-5f;
      float* outm = qkv + ((size_t)wt*6144 + (size_t)n*3 + m)*324;
      outm[i*18 + jj] = acc; outm[jj*18 + i] = acc;
    }
    __syncthreads();
  }
}

// ---------------- K5: batched 18x18 symmetric eigh (tournament Jacobi) + f(A) --------
__global__ __launch_bounds__(256, 4) void k5_jacobi(const float* __restrict__ src, float* __restrict__ dst,
                                                    int nmat, int mode){
  __shared__ __align__(16) float stage[12][384];
  int tid = threadIdx.x;
  int wave = tid >> 6, lane = tid & 63;
  int g = (lane >= 54) ? 3 : (lane >= 36 ? 2 : (lane >= 18 ? 1 : 0));
  int j = lane - g*18;
  int gb = g*18;
  int slot = wave*3 + ((g < 3) ? g : 0);
  int mat = blockIdx.x*12 + wave*3 + g;
  bool act = (g < 3) && (mat < nmat);

  float a[18], u[18], dj;
  if (act){
    const float* s = src + (size_t)mat*324 + j*18;
    #pragma unroll
    for (int i = 0; i < 18; ++i) a[i] = s[i];
  } else {
    #pragma unroll
    for (int i = 0; i < 18; ++i) a[i] = (i == j) ? 1.f : 0.f;
  }
  #pragma unroll
  for (int i = 0; i < 18; ++i) u[i] = (i == j) ? 1.f : 0.f;
  dj = 0.f;
  #pragma unroll
  for (int i = 0; i < 18; ++i) dj = (i == j) ? a[i] : dj;

  #pragma unroll 1
  for (int sweep = 0; sweep < NSWEEP; ++sweep){
    #pragma unroll
    for (int r = 0; r < 17; ++r){
      int xx = j - 1 - r; if (xx < 0) xx += 17;
      int v = r + 17 - xx; if (v >= 17) v -= 17;
      int m = (j == 0) ? (1 + r) : ((xx == 0) ? 0 : (1 + v));
      bool isp = (j == 0) ? true : ((xx == 0) ? false : (xx <= 8));
      float apq_own = 0.f;
      #pragma unroll
      for (int k = 0; k < 18; ++k) apq_own = (k == m) ? a[k] : apq_own;
      int plane = (gb + m) & 63;
      float apq = __shfl(apq_own, isp ? ((gb + j) & 63) : plane);
      float pd = __shfl(dj, plane);
      float app = isp ? dj : pd;
      float aqq = isp ? pd : dj;
      float tau = (aqq - app) * 0.5f * __builtin_amdgcn_rcpf(apq);
      float tt = __builtin_amdgcn_rcpf(fabsf(tau) + sqrtf(fmaf(tau, tau, 1.f)));
      float t = (tau >= 0.f) ? tt : -tt;
      if (!(fabsf(apq) > 1e-36f)) t = 0.f;
      float c = __builtin_amdgcn_rsqf(fmaf(t, t, 1.f));
      float s = t*c;
      dj = isp ? fmaf(-t, apq, app) : fmaf(t, apq, aqq);
      #pragma unroll
      for (int q2 = 0; q2 < 9; ++q2){
        int pl, pr, qr;
        if (q2 == 0){ pl = 0; pr = 0; qr = 1 + r; }
        else { int aa = r + q2; if (aa >= 17) aa -= 17; pl = 1 + aa; pr = pl;
               int bb = r + 17 - q2; if (bb >= 17) bb -= 17; qr = 1 + bb; }
        float cbq = __shfl(c, (gb + pl) & 63);
        float sbq = __shfl(s, (gb + pl) & 63);
        float xv = a[pr], yv = a[qr];
        a[pr] = fmaf(cbq, xv, -sbq*yv);
        a[qr] = fmaf(sbq, xv,  cbq*yv);
        float xu = u[pr], yu = u[qr];
        u[pr] = fmaf(cbq, xu, -sbq*yu);
        u[qr] = fmaf(sbq, xu,  cbq*yu);
      }
      float sgn = isp ? -s : s;
      #pragma unroll
      for (int k = 0; k < 18; ++k){
        float pak = __shfl(a[k], plane);
        a[k] = fmaf(c, a[k], sgn*pak);
      }
    }
  }
  float fl = (mode == 0) ? logf(fmaxf(dj, 1e-12f)) : fmaxf(dj, LOGEPS);
  float* sp = &stage[slot][0];
  if (act){
    #pragma unroll
    for (int k = 0; k < 18; ++k) sp[j*20 + k] = u[k];
    sp[360 + j] = fl;
  }
  __syncthreads();
  if (act){
    float ut[18];
    #pragma unroll
    for (int k = 0; k < 18; ++k) ut[k] = u[k] * sp[360 + k];
    float* orow = dst + (size_t)mat*324 + j*18;
    #pragma unroll
    for (int i = 0; i < 18; ++i){
      const float* ur = &sp[i*20];
      float acc = 0.f;
      #pragma unroll
      for (int k = 0; k < 16; k += 4){
        float4 uv = *(const float4*)&ur[k];
        acc = fmaf(ut[k],   uv.x, acc);
        acc = fmaf(ut[k+1], uv.y, acc);
        acc = fmaf(ut[k+2], uv.z, acc);
        acc = fmaf(ut[k+3], uv.w, acc);
      }
      acc = fmaf(ut[16], ur[16], acc);
      acc = fmaf(ut[17], ur[17], acc);
      orow[i] = acc;
    }
  }
}

// ---------------- K6: energies -> scores -> softmax -> mixed (shuffle-reduced) --------
__global__ __launch_bounds__(128) void k6_attnmix(const float* __restrict__ logs, float* __restrict__ mixed){
  __shared__ float lq[972], lk[972], lv[972];
  __shared__ float ew[2][9];
  __shared__ float P[9];
  int b = blockIdx.x, tid = threadIdx.x;
  const float* q  = logs + (size_t)b*972;
  const float* k_ = logs + 1990656 + (size_t)b*972;
  const float* v_ = logs + 3981312 + (size_t)b*972;
  for (int i = tid; i < 972; i += 128){ lq[i] = q[i]; lk[i] = k_[i]; lv[i] = v_[i]; }
  __syncthreads();
  float e[9] = {0.f,0.f,0.f,0.f,0.f,0.f,0.f,0.f,0.f};
  for (int x = tid; x < 324; x += 128){
    float q0 = lq[x], q1 = lq[324+x], q2 = lq[648+x];
    float k0 = lk[x], k1 = lk[324+x], k2 = lk[648+x];
    float d;
    d = q0-k0; e[0] = fmaf(d,d,e[0]);
    d = q0-k1; e[1] = fmaf(d,d,e[1]);
    d = q0-k2; e[2] = fmaf(d,d,e[2]);
    d = q1-k0; e[3] = fmaf(d,d,e[3]);
    d = q1-k1; e[4] = fmaf(d,d,e[4]);
    d = q1-k2; e[5] = fmaf(d,d,e[5]);
    d = q2-k0; e[6] = fmaf(d,d,e[6]);
    d = q2-k1; e[7] = fmaf(d,d,e[7]);
    d = q2-k2; e[8] = fmaf(d,d,e[8]);
  }
  #pragma unroll
  for (int p = 0; p < 9; ++p)
    for (int off = 32; off; off >>= 1) e[p] += __shfl_down(e[p], off);
  if ((tid & 63) == 0){
    #pragma unroll
    for (int p = 0; p < 9; ++p) ew[tid >> 6][p] = e[p];
  }
  __syncthreads();
  if (tid < 3){
    float en0 = ew[0][tid*3+0] + ew[1][tid*3+0];
    float en1 = ew[0][tid*3+1] + ew[1][tid*3+1];
    float en2 = ew[0][tid*3+2] + ew[1][tid*3+2];
    float s0 = 1.f/(1.f + log1pf(en0));
    float s1 = 1.f/(1.f + log1pf(en1));
    float s2 = 1.f/(1.f + log1pf(en2));
    float mx = fmaxf(s0, fmaxf(s1, s2));
    float e0 = expf(s0-mx), e1 = expf(s1-mx), e2 = expf(s2-mx);
    float inv = 1.f/(e0+e1+e2);
    P[tid*3+0] = e0*inv; P[tid*3+1] = e1*inv; P[tid*3+2] = e2*inv;
  }
  __syncthreads();
  float p00=P[0],p01=P[1],p02=P[2],p10=P[3],p11=P[4],p12=P[5],p20=P[6],p21=P[7],p22=P[8];
  float* mb = mixed + (size_t)b*972;
  for (int x = tid; x < 324; x += 128){
    float v0 = lv[x], v1 = lv[324+x], v2 = lv[648+x];
    mb[x]     = p00*v0 + p01*v1 + p02*v2;
    mb[324+x] = p10*v0 + p11*v1 + p12*v2;
    mb[648+x] = p20*v0 + p21*v1 + p22*v2;
  }
}

// ---------------- K8: triu vectorize + GEMV with Wl + bl ----------------
__global__ __launch_bounds__(64) void k8_out(const float* __restrict__ logO, const float* __restrict__ Wl,
                                             const float* __restrict__ bl, float* __restrict__ outp){
  __shared__ int ti[171], tj[171];
  int b = blockIdx.x, tid = threadIdx.x;
  if (tid < 18){
    int base = tid*(37 - tid)/2;
    for (int jj = tid; jj < 18; ++jj){ ti[base + jj - tid] = tid; tj[base + jj - tid] = jj; }
  }
  __syncthreads();
  float a0=0.f, a1=0.f, a2=0.f, a3=0.f;
  for (int f = tid; f < 513; f += 64){
    int m = f/171, r = f - m*171;
    float vv = logO[(size_t)b*972 + m*324 + ti[r]*18 + tj[r]];
    float4 w = *(const float4*)&Wl[f*4];
    a0 = fmaf(vv, w.x, a0); a1 = fmaf(vv, w.y, a1);
    a2 = fmaf(vv, w.z, a2); a3 = fmaf(vv, w.w, a3);
  }
  for (int off = 32; off; off >>= 1){
    a0 += __shfl_down(a0, off); a1 += __shfl_down(a1, off);
    a2 += __shfl_down(a2, off); a3 += __shfl_down(a3, off);
  }
  if (tid == 0){
    float4 r = { a0 + bl[0], a1 + bl[1], a2 + bl[2], a3 + bl[3] };
    *(float4*)&outp[b*4] = r;
  }
}

// ---------------- launcher ----------------
extern "C" void kernel_launch(void* const* d_in, const int* in_sizes, int n_in,
                              void* d_out, int out_size, void* d_ws, size_t ws_size,
                              hipStream_t stream){
  (void)in_sizes; (void)n_in; (void)out_size; (void)ws_size;
  const float* x   = (const float*)d_in[0];
  const float* W1  = (const float*)d_in[1];
  const float* g1  = (const float*)d_in[3];
  const float* be1 = (const float*)d_in[4];
  const float* W2  = (const float*)d_in[5];
  const float* g2  = (const float*)d_in[7];
  const float* Wq  = (const float*)d_in[9];
  const float* Wk  = (const float*)d_in[10];
  const float* Wv  = (const float*)d_in[11];
  const float* Wl  = (const float*)d_in[12];
  const float* bl  = (const float*)d_in[13];
  float* ws    = (float*)d_ws;
  float* y2    = ws + OFF_Y2;
  float* qkv   = ws + OFF_QKV;
  float* logs  = ws + OFF_Y2;    // overlay: y2 dead after k4
  float* mixed = ws + OFF_QKV;   // overlay: qkv dead after k5#1
  float* logO  = ws + OFF_LOGO;
  float* st    = ws + OFF_ST;
  float* outp  = (float*)d_out;

  k0_zero   <<<dim3(1),        dim3(256), 0, stream>>>(st);
  k1_xstats <<<dim3(2048),     dim3(256), 0, stream>>>(x, st);
  k1b_fold  <<<dim3(1),        dim3(64),  0, stream>>>(W1, g1, be1, st);
  k3_conv   <<<dim3(2048),     dim3(512), 0, stream>>>(x, W2, st, y2);
  k3b_y2stats<<<dim3(20,16),   dim3(256), 0, stream>>>(y2, st);
  k4_cov_qkv<<<dim3(2048),     dim3(256), 0, stream>>>(y2, st, g2, Wq, Wk, Wv, qkv);
  k5_jacobi <<<dim3(1536),     dim3(256), 0, stream>>>(qkv, logs, 18432, 0);
  k6_attnmix<<<dim3(2048),     dim3(128), 0, stream>>>(logs, mixed);
  k5_jacobi <<<dim3(512),      dim3(256), 0, stream>>>(mixed, logO, 6144, 1);
  k8_out    <<<dim3(2048),     dim3(64),  0, stream>>>(logO, Wl, bl, outp);
}

// Round 4
// 936.057 us; speedup vs baseline: 1.1167x; 1.1167x over previous
//
#include <hip/hip_runtime.h>
#include <math.h>

// ---------------- workspace layout (floats) ----------------
#define OFF_Y2   0
#define OFF_QKV  17981440
#define OFF_LOGO (17981440 + 1990656)
#define OFF_ST   (17981440 + 5971968)
// stats offsets
#define ST_SX   0
#define ST_SXX  22
#define ST_WF   506
#define ST_BF   990
#define ST_Y2S  1012
#define ST_Y2Q  1032
#define ST_TOT  1052

#define LOGEPS -9.210340371976182f
#define NSWEEP 5

// ---------------- K0: zero stats ----------------
__global__ __launch_bounds__(256) void k0_zero(float* __restrict__ st){
  for (int i = threadIdx.x; i < ST_TOT; i += 256) st[i] = 0.f;
}

// ---------------- K1: x second moments (for closed-form BN1 stats) ----------------
__global__ __launch_bounds__(256) void k1_xstats(const float* __restrict__ x, float* __restrict__ st){
  __shared__ __align__(16) float xs[22*444];
  const float* xb = x + (size_t)blockIdx.x * (22*438);
  for (int i = threadIdx.x; i < 22*444; i += 256){
    int h = i / 444, w = i - h*444;
    xs[i] = (w < 438) ? xb[h*438 + w] : 0.f;
  }
  __syncthreads();
  for (int t = threadIdx.x; t < 275; t += 256){
    if (t < 22){
      const float4* r = (const float4*)&xs[t*444];
      float4 acc = {0.f,0.f,0.f,0.f};
      for (int w = 0; w < 111; ++w){ float4 v = r[w]; acc.x+=v.x; acc.y+=v.y; acc.z+=v.z; acc.w+=v.w; }
      atomicAdd(&st[ST_SX + t], acc.x+acc.y+acc.z+acc.w);
    } else {
      int rem = t - 22, h = 0;
      while (rem >= 22 - h){ rem -= 22 - h; ++h; }
      int h2 = h + rem;
      const float4* ra = (const float4*)&xs[h*444];
      const float4* rb = (const float4*)&xs[h2*444];
      float4 acc = {0.f,0.f,0.f,0.f};
      for (int w = 0; w < 111; ++w){
        float4 a = ra[w], b = rb[w];
        acc.x = fmaf(a.x,b.x,acc.x); acc.y = fmaf(a.y,b.y,acc.y);
        acc.z = fmaf(a.z,b.z,acc.z); acc.w = fmaf(a.w,b.w,acc.w);
      }
      atomicAdd(&st[ST_SXX + h*22 + h2], acc.x+acc.y+acc.z+acc.w);
    }
  }
}

// ---------------- K1b: fold BN1 into conv1 weights ----------------
__global__ __launch_bounds__(64) void k1b_fold(const float* __restrict__ W1, const float* __restrict__ g1,
                                               const float* __restrict__ be1, float* __restrict__ st){
  int c = threadIdx.x;
  if (c >= 22) return;
  const float invN = 1.f / (2048.f*438.f);
  float mcol[22];
  float mu0 = 0.f;
  for (int h = 0; h < 22; ++h){ mcol[h] = W1[c*22 + h]; mu0 = fmaf(mcol[h], st[ST_SX + h], mu0); }
  mu0 *= invN;
  float qf = 0.f;
  for (int h = 0; h < 22; ++h)
    for (int h2 = h; h2 < 22; ++h2){
      float w = mcol[h]*mcol[h2]*st[ST_SXX + h*22 + h2];
      qf += (h2 == h) ? w : 2.f*w;
    }
  qf *= invN;
  float var = qf - mu0*mu0;
  float a1 = g1[c] * rsqrtf(var + 1e-5f);
  for (int h = 0; h < 22; ++h) st[ST_WF + h*22 + c] = a1 * mcol[h];
  st[ST_BF + c] = be1[c] - a1 * mu0;   // b1 cancels exactly
}

// ---------------- K3: fused conv1+BN1+conv2 ----------------
// conv2 lane mapping is d-fast (d = tid%20): 20 consecutive lanes share one
// z-window -> LDS broadcast (free). chunk-fast was a 16-way bank conflict
// (stride 24 floats, 24 mod 32 -> 4 bank-groups) = 8.6e7 conflicts, 3x slower.
__global__ __launch_bounds__(512) void k3_conv(const float* __restrict__ x, const float* __restrict__ W2,
                                               const float* __restrict__ st, float* __restrict__ y2){
  __shared__ __align__(16) float zs[22*452 + 20];  // +20: OOB-read slack for 36-float windows
  __shared__ __align__(16) float w2s[20*268];
  __shared__ __align__(16) float wfs[22*24];
  __shared__ float bfs[22];
  int tid = threadIdx.x;
  int n = blockIdx.x;
  for (int i = tid; i < 484; i += 512){ int h = i/22, c = i - h*22; wfs[h*24 + c] = st[ST_WF + i]; }
  for (int i = tid; i < 5280; i += 512){ int d = i/264, r = i - d*264; w2s[d*268 + r] = W2[i]; }
  if (tid < 22) bfs[tid] = st[ST_BF + tid];
  for (int i = tid; i < 22*14; i += 512){ int c = i/14, k = i - c*14; int w = (k < 6) ? k : (438 + k); zs[c*452 + w] = 0.f; }
  __syncthreads();
  if (tid < 438){
    float acc[22];
    #pragma unroll
    for (int c = 0; c < 22; ++c) acc[c] = bfs[c];
    const float* xb = x + (size_t)n*(22*438) + tid;
    #pragma unroll 1
    for (int h = 0; h < 22; ++h){
      float xv = xb[h*438];
      #pragma unroll
      for (int c = 0; c < 22; ++c) acc[c] = fmaf(wfs[h*24 + c], xv, acc[c]);
    }
    #pragma unroll
    for (int c = 0; c < 22; ++c) zs[c*452 + tid + 6] = acc[c];
  }
  __syncthreads();
  // conv2: 380 threads = 19 chunks x 20 d, d-fast
  if (tid < 380){
    int chunk = tid / 20, d = tid - chunk*20;
    int w0 = chunk*24;
    float acc[24];
    #pragma unroll
    for (int jj = 0; jj < 24; ++jj) acc[jj] = 0.f;
    #pragma unroll 1
    for (int c = 0; c < 22; ++c){
      const float* zr = &zs[c*452 + w0];
      float zw[36];
      #pragma unroll
      for (int k = 0; k < 36; k += 4){ float4 v = *(const float4*)&zr[k]; zw[k]=v.x; zw[k+1]=v.y; zw[k+2]=v.z; zw[k+3]=v.w; }
      const float* wr = &w2s[d*268 + c*12];
      float wt[12];
      #pragma unroll
      for (int t = 0; t < 12; t += 4){ float4 v = *(const float4*)&wr[t]; wt[t]=v.x; wt[t+1]=v.y; wt[t+2]=v.z; wt[t+3]=v.w; }
      #pragma unroll
      for (int jj = 0; jj < 24; ++jj)
        #pragma unroll
        for (int t = 0; t < 12; ++t)
          acc[jj] = fmaf(wt[t], zw[jj+t], acc[jj]);
    }
    float* yb = y2 + (size_t)n*8780 + d*439;
    #pragma unroll
    for (int jj = 0; jj < 24; ++jj){ int w = w0 + jj; if (w < 439) yb[w] = acc[jj]; }
  }
}

// ---------------- K3b: y2 per-channel sum/sumsq ----------------
__global__ __launch_bounds__(256) void k3b_y2stats(const float* __restrict__ y2, float* __restrict__ st){
  int d = blockIdx.x, chunk = blockIdx.y;
  float sum = 0.f, sq = 0.f;
  for (int n = chunk*128; n < chunk*128 + 128; ++n){
    const float* r = y2 + (size_t)n*8780 + d*439;
    for (int w = threadIdx.x; w < 439; w += 256){ float v = r[w]; sum += v; sq = fmaf(v, v, sq); }
  }
  __shared__ float red[4][2];
  for (int off = 32; off; off >>= 1){ sum += __shfl_down(sum, off); sq += __shfl_down(sq, off); }
  int wid = threadIdx.x >> 6;
  if ((threadIdx.x & 63) == 0){ red[wid][0] = sum; red[wid][1] = sq; }
  __syncthreads();
  if (threadIdx.x == 0){
    float s = 0.f, q = 0.f;
    for (int i = 0; i < 4; ++i){ s += red[i][0]; q += red[i][1]; }
    atomicAdd(&st[ST_Y2S + d], s);
    atomicAdd(&st[ST_Y2Q + d], q);
  }
}

// ---------------- K4: covariance + Q/K/V congruence (patch-split LDS, float4 dots) ------
__global__ __launch_bounds__(256) void k4_cov_qkv(const float* __restrict__ y2, const float* __restrict__ st,
    const float* __restrict__ g2, const float* __restrict__ Wq, const float* __restrict__ Wk,
    const float* __restrict__ Wv, float* __restrict__ qkv){
  __shared__ __align__(16) float ysp[3][20][148];  // patch-split, zero-padded to 148
  __shared__ float a2s[20];
  __shared__ __align__(16) float Bt[3][18][20];    // [wt][i][d] = a2[d]*W[d][i]
  __shared__ __align__(16) float G3[3][400];
  __shared__ __align__(16) float Tmt[3][360];      // [m][jj*20+p]
  __shared__ float musum3[3][20];
  __shared__ float rtr3[3];
  int tid = threadIdx.x, n = blockIdx.x;
  if (tid < 20){
    const float invN = 1.f/(2048.f*439.f);
    float s = st[ST_Y2S + tid]*invN;
    float q = st[ST_Y2Q + tid]*invN;
    a2s[tid] = g2[tid] * rsqrtf(q - s*s + 1e-5f);
  }
  const float* yb = y2 + (size_t)n*8780;
  for (int i = tid; i < 8780; i += 256){
    int d = i/439, w = i - d*439;
    int m = (w >= 293) ? 2 : ((w >= 147) ? 1 : 0);
    int lw = w - ((m == 2) ? 293 : ((m == 1) ? 147 : 0));
    ysp[m][d][lw] = yb[i];
  }
  if (tid < 100){   // zero the pad slots
    int d = tid/5, k = tid - d*5;
    int m = (k == 0) ? 0 : ((k < 3) ? 1 : 2);
    int lw = (k == 0) ? 147 : ((k == 1 || k == 3) ? 146 : 147);
    ysp[m][d][lw] = 0.f;
  }
  __syncthreads();
  // Bt (1080) + musum (60)
  for (int i = tid; i < 1140; i += 256){
    if (i < 1080){
      int wt = i/360, r = i - wt*360; int d = r/18, jj = r - d*18;
      const float* Wm = (wt==0) ? Wq : ((wt==1) ? Wk : Wv);
      Bt[wt][jj][d] = a2s[d]*Wm[d*18 + jj];
    } else {
      int t = i - 1080; int m = t/20, d = t - m*20;
      const float4* r = (const float4*)&ysp[m][d][0];
      float4 acc = {0.f,0.f,0.f,0.f};
      #pragma unroll 1
      for (int w = 0; w < 37; ++w){ float4 v = r[w]; acc.x+=v.x; acc.y+=v.y; acc.z+=v.z; acc.w+=v.w; }
      musum3[m][d] = acc.x+acc.y+acc.z+acc.w;
    }
  }
  __syncthreads();
  // covariance pairs: 630 items (3 patches x 210 pairs), float4 dots
  for (int it = tid; it < 630; it += 256){
    int m = it/210, t = it - m*210;
    int rem = t, c = 0;
    while (rem >= 20 - c){ rem -= 20 - c; ++c; }
    int d = c + rem;
    const float4* ra = (const float4*)&ysp[m][c][0];
    const float4* rb = (const float4*)&ysp[m][d][0];
    float4 acc4 = {0.f,0.f,0.f,0.f};
    #pragma unroll 1
    for (int w = 0; w < 37; ++w){
      float4 a = ra[w], b = rb[w];
      acc4.x = fmaf(a.x,b.x,acc4.x); acc4.y = fmaf(a.y,b.y,acc4.y);
      acc4.z = fmaf(a.z,b.z,acc4.z); acc4.w = fmaf(a.w,b.w,acc4.w);
    }
    float invL = (m == 0) ? (1.f/147.f) : (1.f/146.f);
    float acc = (acc4.x+acc4.y+acc4.z+acc4.w) - musum3[m][c]*musum3[m][d]*invL;
    G3[m][c*20 + d] = acc; G3[m][d*20 + c] = acc;
  }
  __syncthreads();
  for (int wt = 0; wt < 3; ++wt){
    // Tm pass (1080 items) + rtr (3, first wt only)
    for (int i = tid; i < 1083; i += 256){
      if (i < 1080){
        int m = i/360, r = i - m*360; int p = r/18, jj = r - p*18;
        const float4* gr = (const float4*)&G3[m][p*20];
        const float4* br = (const float4*)&Bt[wt][jj][0];
        float4 a4 = {0.f,0.f,0.f,0.f};
        #pragma unroll
        for (int w = 0; w < 5; ++w){
          float4 a = gr[w], b = br[w];
          a4.x = fmaf(a.x,b.x,a4.x); a4.y = fmaf(a.y,b.y,a4.y);
          a4.z = fmaf(a.z,b.z,a4.z); a4.w = fmaf(a.w,b.w,a4.w);
        }
        Tmt[m][jj*20 + p] = a4.x+a4.y+a4.z+a4.w;
      } else if (wt == 0){
        int m = i - 1080;
        float tr = 0.f;
        for (int c = 0; c < 20; ++c){ float a = a2s[c]; tr = fmaf(a*a, G3[m][c*21], tr); }
        rtr3[m] = 1.f/tr;
      }
    }
    __syncthreads();
    // final pass: 513 items (3 m x 171 triu)
    for (int it = tid; it < 513; it += 256){
      int m = it/171, t = it - m*171;
      int rem = t, i = 0;
      while (rem >= 18 - i){ rem -= 18 - i; ++i; }
      int jj = i + rem;
      const float4* br = (const float4*)&Bt[wt][i][0];
      const float4* tr = (const float4*)&Tmt[m][jj*20];
      float4 a4 = {0.f,0.f,0.f,0.f};
      #pragma unroll
      for (int w = 0; w < 5; ++w){
        float4 a = br[w], b = tr[w];
        a4.x = fmaf(a.x,b.x,a4.x); a4.y = fmaf(a.y,b.y,a4.y);
        a4.z = fmaf(a.z,b.z,a4.z); a4.w = fmaf(a.w,b.w,a4.w);
      }
      float acc = (a4.x+a4.y+a4.z+a4.w) * rtr3[m];
      if (i == jj) acc += 1e-5f;
      float* outm = qkv + ((size_t)wt*6144 + (size_t)n*3 + m)*324;
      outm[i*18 + jj] = acc; outm[jj*18 + i] = acc;
    }
    __syncthreads();
  }
}

// ---------------- K5: batched 18x18 symmetric eigh (tournament Jacobi) + f(A) --------
__global__ __launch_bounds__(256, 4) void k5_jacobi(const float* __restrict__ src, float* __restrict__ dst,
                                                    int nmat, int mode){
  __shared__ __align__(16) float stage[12][384];
  int tid = threadIdx.x;
  int wave = tid >> 6, lane = tid & 63;
  int g = (lane >= 54) ? 3 : (lane >= 36 ? 2 : (lane >= 18 ? 1 : 0));
  int j = lane - g*18;
  int gb = g*18;
  int slot = wave*3 + ((g < 3) ? g : 0);
  int mat = blockIdx.x*12 + wave*3 + g;
  bool act = (g < 3) && (mat < nmat);

  float a[18], u[18], dj;
  if (act){
    const float* s = src + (size_t)mat*324 + j*18;
    #pragma unroll
    for (int i = 0; i < 18; ++i) a[i] = s[i];
  } else {
    #pragma unroll
    for (int i = 0; i < 18; ++i) a[i] = (i == j) ? 1.f : 0.f;
  }
  #pragma unroll
  for (int i = 0; i < 18; ++i) u[i] = (i == j) ? 1.f : 0.f;
  dj = 0.f;
  #pragma unroll
  for (int i = 0; i < 18; ++i) dj = (i == j) ? a[i] : dj;

  #pragma unroll 1
  for (int sweep = 0; sweep < NSWEEP; ++sweep){
    #pragma unroll
    for (int r = 0; r < 17; ++r){
      int xx = j - 1 - r; if (xx < 0) xx += 17;
      int v = r + 17 - xx; if (v >= 17) v -= 17;
      int m = (j == 0) ? (1 + r) : ((xx == 0) ? 0 : (1 + v));
      bool isp = (j == 0) ? true : ((xx == 0) ? false : (xx <= 8));
      float apq_own = 0.f;
      #pragma unroll
      for (int k = 0; k < 18; ++k) apq_own = (k == m) ? a[k] : apq_own;
      int plane = (gb + m) & 63;
      float apq = __shfl(apq_own, isp ? ((gb + j) & 63) : plane);
      float pd = __shfl(dj, plane);
      float app = isp ? dj : pd;
      float aqq = isp ? pd : dj;
      float tau = (aqq - app) * 0.5f * __builtin_amdgcn_rcpf(apq);
      float tt = __builtin_amdgcn_rcpf(fabsf(tau) + sqrtf(fmaf(tau, tau, 1.f)));
      float t = (tau >= 0.f) ? tt : -tt;
      if (!(fabsf(apq) > 1e-36f)) t = 0.f;
      float c = __builtin_amdgcn_rsqf(fmaf(t, t, 1.f));
      float s = t*c;
      dj = isp ? fmaf(-t, apq, app) : fmaf(t, apq, aqq);
      #pragma unroll
      for (int q2 = 0; q2 < 9; ++q2){
        int pl, pr, qr;
        if (q2 == 0){ pl = 0; pr = 0; qr = 1 + r; }
        else { int aa = r + q2; if (aa >= 17) aa -= 17; pl = 1 + aa; pr = pl;
               int bb = r + 17 - q2; if (bb >= 17) bb -= 17; qr = 1 + bb; }
        float cbq = __shfl(c, (gb + pl) & 63);
        float sbq = __shfl(s, (gb + pl) & 63);
        float xv = a[pr], yv = a[qr];
        a[pr] = fmaf(cbq, xv, -sbq*yv);
        a[qr] = fmaf(sbq, xv,  cbq*yv);
        float xu = u[pr], yu = u[qr];
        u[pr] = fmaf(cbq, xu, -sbq*yu);
        u[qr] = fmaf(sbq, xu,  cbq*yu);
      }
      float sgn = isp ? -s : s;
      #pragma unroll
      for (int k = 0; k < 18; ++k){
        float pak = __shfl(a[k], plane);
        a[k] = fmaf(c, a[k], sgn*pak);
      }
    }
  }
  float fl = (mode == 0) ? logf(fmaxf(dj, 1e-12f)) : fmaxf(dj, LOGEPS);
  float* sp = &stage[slot][0];
  if (act){
    #pragma unroll
    for (int k = 0; k < 18; ++k) sp[j*20 + k] = u[k];
    sp[360 + j] = fl;
  }
  __syncthreads();
  if (act){
    float ut[18];
    #pragma unroll
    for (int k = 0; k < 18; ++k) ut[k] = u[k] * sp[360 + k];
    float* orow = dst + (size_t)mat*324 + j*18;
    #pragma unroll
    for (int i = 0; i < 18; ++i){
      const float* ur = &sp[i*20];
      float acc = 0.f;
      #pragma unroll
      for (int k = 0; k < 16; k += 4){
        float4 uv = *(const float4*)&ur[k];
        acc = fmaf(ut[k],   uv.x, acc);
        acc = fmaf(ut[k+1], uv.y, acc);
        acc = fmaf(ut[k+2], uv.z, acc);
        acc = fmaf(ut[k+3], uv.w, acc);
      }
      acc = fmaf(ut[16], ur[16], acc);
      acc = fmaf(ut[17], ur[17], acc);
      orow[i] = acc;
    }
  }
}

// ---------------- K6: energies -> scores -> softmax -> mixed (shuffle-reduced) --------
__global__ __launch_bounds__(128) void k6_attnmix(const float* __restrict__ logs, float* __restrict__ mixed){
  __shared__ float lq[972], lk[972], lv[972];
  __shared__ float ew[2][9];
  __shared__ float P[9];
  int b = blockIdx.x, tid = threadIdx.x;
  const float* q  = logs + (size_t)b*972;
  const float* k_ = logs + 1990656 + (size_t)b*972;
  const float* v_ = logs + 3981312 + (size_t)b*972;
  for (int i = tid; i < 972; i += 128){ lq[i] = q[i]; lk[i] = k_[i]; lv[i] = v_[i]; }
  __syncthreads();
  float e[9] = {0.f,0.f,0.f,0.f,0.f,0.f,0.f,0.f,0.f};
  for (int x = tid; x < 324; x += 128){
    float q0 = lq[x], q1 = lq[324+x], q2 = lq[648+x];
    float k0 = lk[x], k1 = lk[324+x], k2 = lk[648+x];
    float d;
    d = q0-k0; e[0] = fmaf(d,d,e[0]);
    d = q0-k1; e[1] = fmaf(d,d,e[1]);
    d = q0-k2; e[2] = fmaf(d,d,e[2]);
    d = q1-k0; e[3] = fmaf(d,d,e[3]);
    d = q1-k1; e[4] = fmaf(d,d,e[4]);
    d = q1-k2; e[5] = fmaf(d,d,e[5]);
    d = q2-k0; e[6] = fmaf(d,d,e[6]);
    d = q2-k1; e[7] = fmaf(d,d,e[7]);
    d = q2-k2; e[8] = fmaf(d,d,e[8]);
  }
  #pragma unroll
  for (int p = 0; p < 9; ++p)
    for (int off = 32; off; off >>= 1) e[p] += __shfl_down(e[p], off);
  if ((tid & 63) == 0){
    #pragma unroll
    for (int p = 0; p < 9; ++p) ew[tid >> 6][p] = e[p];
  }
  __syncthreads();
  if (tid < 3){
    float en0 = ew[0][tid*3+0] + ew[1][tid*3+0];
    float en1 = ew[0][tid*3+1] + ew[1][tid*3+1];
    float en2 = ew[0][tid*3+2] + ew[1][tid*3+2];
    float s0 = 1.f/(1.f + log1pf(en0));
    float s1 = 1.f/(1.f + log1pf(en1));
    float s2 = 1.f/(1.f + log1pf(en2));
    float mx = fmaxf(s0, fmaxf(s1, s2));
    float e0 = expf(s0-mx), e1 = expf(s1-mx), e2 = expf(s2-mx);
    float inv = 1.f/(e0+e1+e2);
    P[tid*3+0] = e0*inv; P[tid*3+1] = e1*inv; P[tid*3+2] = e2*inv;
  }
  __syncthreads();
  float p00=P[0],p01=P[1],p02=P[2],p10=P[3],p11=P[4],p12=P[5],p20=P[6],p21=P[7],p22=P[8];
  float* mb = mixed + (size_t)b*972;
  for (int x = tid; x < 324; x += 128){
    float v0 = lv[x], v1 = lv[324+x], v2 = lv[648+x];
    mb[x]     = p00*v0 + p01*v1 + p02*v2;
    mb[324+x] = p10*v0 + p11*v1 + p12*v2;
    mb[648+x] = p20*v0 + p21*v1 + p22*v2;
  }
}

// ---------------- K8: triu vectorize + GEMV with Wl + bl ----------------
__global__ __launch_bounds__(64) void k8_out(const float* __restrict__ logO, const float* __restrict__ Wl,
                                             const float* __restrict__ bl, float* __restrict__ outp){
  __shared__ int ti[171], tj[171];
  int b = blockIdx.x, tid = threadIdx.x;
  if (tid < 18){
    int base = tid*(37 - tid)/2;
    for (int jj = tid; jj < 18; ++jj){ ti[base + jj - tid] = tid; tj[base + jj - tid] = jj; }
  }
  __syncthreads();
  float a0=0.f, a1=0.f, a2=0.f, a3=0.f;
  for (int f = tid; f < 513; f += 64){
    int m = f/171, r = f - m*171;
    float vv = logO[(size_t)b*972 + m*324 + ti[r]*18 + tj[r]];
    float4 w = *(const float4*)&Wl[f*4];
    a0 = fmaf(vv, w.x, a0); a1 = fmaf(vv, w.y, a1);
    a2 = fmaf(vv, w.z, a2); a3 = fmaf(vv, w.w, a3);
  }
  for (int off = 32; off; off >>= 1){
    a0 += __shfl_down(a0, off); a1 += __shfl_down(a1, off);
    a2 += __shfl_down(a2, off); a3 += __shfl_down(a3, off);
  }
  if (tid == 0){
    float4 r = { a0 + bl[0], a1 + bl[1], a2 + bl[2], a3 + bl[3] };
    *(float4*)&outp[b*4] = r;
  }
}

// ---------------- launcher ----------------
extern "C" void kernel_launch(void* const* d_in, const int* in_sizes, int n_in,
                              void* d_out, int out_size, void* d_ws, size_t ws_size,
                              hipStream_t stream){
  (void)in_sizes; (void)n_in; (void)out_size; (void)ws_size;
  const float* x   = (const float*)d_in[0];
  const float* W1  = (const float*)d_in[1];
  const float* g1  = (const float*)d_in[3];
  const float* be1 = (const float*)d_in[4];
  const float* W2  = (const float*)d_in[5];
  const float* g2  = (const float*)d_in[7];
  const float* Wq  = (const float*)d_in[9];
  const float* Wk  = (const float*)d_in[10];
  const float* Wv  = (const float*)d_in[11];
  const float* Wl  = (const float*)d_in[12];
  const float* bl  = (const float*)d_in[13];
  float* ws    = (float*)d_ws;
  float* y2    = ws + OFF_Y2;
  float* qkv   = ws + OFF_QKV;
  float* logs  = ws + OFF_Y2;    // overlay: y2 dead after k4
  float* mixed = ws + OFF_QKV;   // overlay: qkv dead after k5#1
  float* logO  = ws + OFF_LOGO;
  float* st    = ws + OFF_ST;
  float* outp  = (float*)d_out;

  k0_zero   <<<dim3(1),        dim3(256), 0, stream>>>(st);
  k1_xstats <<<dim3(2048),     dim3(256), 0, stream>>>(x, st);
  k1b_fold  <<<dim3(1),        dim3(64),  0, stream>>>(W1, g1, be1, st);
  k3_conv   <<<dim3(2048),     dim3(512), 0, stream>>>(x, W2, st, y2);
  k3b_y2stats<<<dim3(20,16),   dim3(256), 0, stream>>>(y2, st);
  k4_cov_qkv<<<dim3(2048),     dim3(256), 0, stream>>>(y2, st, g2, Wq, Wk, Wv, qkv);
  k5_jacobi <<<dim3(1536),     dim3(256), 0, stream>>>(qkv, logs, 18432, 0);
  k6_attnmix<<<dim3(2048),     dim3(128), 0, stream>>>(logs, mixed);
  k5_jacobi <<<dim3(512),      dim3(256), 0, stream>>>(mixed, logO, 6144, 1);
  k8_out    <<<dim3(2048),     dim3(64),  0, stream>>>(logO, Wl, bl, outp);
}

// Round 5
// 749.447 us; speedup vs baseline: 1.3948x; 1.2490x over previous
//
#include <hip/hip_runtime.h>
#include <math.h>

// ---------------- workspace layout (floats) ----------------
#define OFF_Y2   0
#define OFF_QKV  17981440
#define OFF_ST   (17981440 + 5971968)
// stats offsets
#define ST_SX   0
#define ST_SXX  22
#define ST_WF   506
#define ST_BF   990
#define ST_Y2S  1012
#define ST_Y2Q  1032
#define ST_TOT  1052

#define LOGEPS -9.210340371976182f
#define NSWEEP 5
#define SHIFT  12.0f   // mixed eigenvalues in [-11.62, ~1e-4] -> shifted PSD

// ---------------- K0: zero stats ----------------
__global__ __launch_bounds__(256) void k0_zero(float* __restrict__ st){
  for (int i = threadIdx.x; i < ST_TOT; i += 256) st[i] = 0.f;
}

// ---------------- K1: x second moments (for closed-form BN1 stats) ----------------
__global__ __launch_bounds__(256) void k1_xstats(const float* __restrict__ x, float* __restrict__ st){
  __shared__ __align__(16) float xs[22*444];
  const float* xb = x + (size_t)blockIdx.x * (22*438);
  for (int i = threadIdx.x; i < 22*444; i += 256){
    int h = i / 444, w = i - h*444;
    xs[i] = (w < 438) ? xb[h*438 + w] : 0.f;
  }
  __syncthreads();
  for (int t = threadIdx.x; t < 275; t += 256){
    if (t < 22){
      const float4* r = (const float4*)&xs[t*444];
      float4 acc = {0.f,0.f,0.f,0.f};
      for (int w = 0; w < 111; ++w){ float4 v = r[w]; acc.x+=v.x; acc.y+=v.y; acc.z+=v.z; acc.w+=v.w; }
      atomicAdd(&st[ST_SX + t], acc.x+acc.y+acc.z+acc.w);
    } else {
      int rem = t - 22, h = 0;
      while (rem >= 22 - h){ rem -= 22 - h; ++h; }
      int h2 = h + rem;
      const float4* ra = (const float4*)&xs[h*444];
      const float4* rb = (const float4*)&xs[h2*444];
      float4 acc = {0.f,0.f,0.f,0.f};
      for (int w = 0; w < 111; ++w){
        float4 a = ra[w], b = rb[w];
        acc.x = fmaf(a.x,b.x,acc.x); acc.y = fmaf(a.y,b.y,acc.y);
        acc.z = fmaf(a.z,b.z,acc.z); acc.w = fmaf(a.w,b.w,acc.w);
      }
      atomicAdd(&st[ST_SXX + h*22 + h2], acc.x+acc.y+acc.z+acc.w);
    }
  }
}

// ---------------- K1b: fold BN1 into conv1 weights ----------------
__global__ __launch_bounds__(64) void k1b_fold(const float* __restrict__ W1, const float* __restrict__ g1,
                                               const float* __restrict__ be1, float* __restrict__ st){
  int c = threadIdx.x;
  if (c >= 22) return;
  const float invN = 1.f / (2048.f*438.f);
  float mcol[22];
  float mu0 = 0.f;
  for (int h = 0; h < 22; ++h){ mcol[h] = W1[c*22 + h]; mu0 = fmaf(mcol[h], st[ST_SX + h], mu0); }
  mu0 *= invN;
  float qf = 0.f;
  for (int h = 0; h < 22; ++h)
    for (int h2 = h; h2 < 22; ++h2){
      float w = mcol[h]*mcol[h2]*st[ST_SXX + h*22 + h2];
      qf += (h2 == h) ? w : 2.f*w;
    }
  qf *= invN;
  float var = qf - mu0*mu0;
  float a1 = g1[c] * rsqrtf(var + 1e-5f);
  for (int h = 0; h < 22; ++h) st[ST_WF + h*22 + c] = a1 * mcol[h];
  st[ST_BF + c] = be1[c] - a1 * mu0;   // b1 cancels exactly
}

// ---------------- K3: fused conv1+BN1+conv2 ----------------
// __launch_bounds__(512, 2): live set is acc[24]+zw[36]+wt[12] ~= 82 VGPR;
// the default bound capped at 60 -> scratch spills (~1.4 GB traffic, ~200+ us).
// d-fast lane mapping: 20 consecutive lanes share one z-window (LDS broadcast).
__global__ __launch_bounds__(512, 2) void k3_conv(const float* __restrict__ x, const float* __restrict__ W2,
                                                  const float* __restrict__ st, float* __restrict__ y2){
  __shared__ __align__(16) float zs[22*452 + 20];  // +20: OOB-read slack for 36-float windows
  __shared__ __align__(16) float w2s[20*268];
  __shared__ __align__(16) float wfs[22*24];
  __shared__ float bfs[22];
  int tid = threadIdx.x;
  int n = blockIdx.x;
  for (int i = tid; i < 484; i += 512){ int h = i/22, c = i - h*22; wfs[h*24 + c] = st[ST_WF + i]; }
  for (int i = tid; i < 5280; i += 512){ int d = i/264, r = i - d*264; w2s[d*268 + r] = W2[i]; }
  if (tid < 22) bfs[tid] = st[ST_BF + tid];
  for (int i = tid; i < 22*14; i += 512){ int c = i/14, k = i - c*14; int w = (k < 6) ? k : (438 + k); zs[c*452 + w] = 0.f; }
  __syncthreads();
  if (tid < 438){
    float acc[22];
    #pragma unroll
    for (int c = 0; c < 22; ++c) acc[c] = bfs[c];
    const float* xb = x + (size_t)n*(22*438) + tid;
    #pragma unroll 1
    for (int h = 0; h < 22; ++h){
      float xv = xb[h*438];
      #pragma unroll
      for (int c = 0; c < 22; ++c) acc[c] = fmaf(wfs[h*24 + c], xv, acc[c]);
    }
    #pragma unroll
    for (int c = 0; c < 22; ++c) zs[c*452 + tid + 6] = acc[c];
  }
  __syncthreads();
  // conv2: 380 threads = 19 chunks x 20 d, d-fast
  if (tid < 380){
    int chunk = tid / 20, d = tid - chunk*20;
    int w0 = chunk*24;
    float acc[24];
    #pragma unroll
    for (int jj = 0; jj < 24; ++jj) acc[jj] = 0.f;
    #pragma unroll 1
    for (int c = 0; c < 22; ++c){
      const float* zr = &zs[c*452 + w0];
      float zw[36];
      #pragma unroll
      for (int k = 0; k < 36; k += 4){ float4 v = *(const float4*)&zr[k]; zw[k]=v.x; zw[k+1]=v.y; zw[k+2]=v.z; zw[k+3]=v.w; }
      const float* wr = &w2s[d*268 + c*12];
      float wt[12];
      #pragma unroll
      for (int t = 0; t < 12; t += 4){ float4 v = *(const float4*)&wr[t]; wt[t]=v.x; wt[t+1]=v.y; wt[t+2]=v.z; wt[t+3]=v.w; }
      #pragma unroll
      for (int jj = 0; jj < 24; ++jj)
        #pragma unroll
        for (int t = 0; t < 12; ++t)
          acc[jj] = fmaf(wt[t], zw[jj+t], acc[jj]);
    }
    float* yb = y2 + (size_t)n*8780 + d*439;
    #pragma unroll
    for (int jj = 0; jj < 24; ++jj){ int w = w0 + jj; if (w < 439) yb[w] = acc[jj]; }
  }
}

// ---------------- K3b: y2 per-channel sum/sumsq ----------------
__global__ __launch_bounds__(256) void k3b_y2stats(const float* __restrict__ y2, float* __restrict__ st){
  int d = blockIdx.x, chunk = blockIdx.y;
  float sum = 0.f, sq = 0.f;
  for (int n = chunk*128; n < chunk*128 + 128; ++n){
    const float* r = y2 + (size_t)n*8780 + d*439;
    for (int w = threadIdx.x; w < 439; w += 256){ float v = r[w]; sum += v; sq = fmaf(v, v, sq); }
  }
  __shared__ float red[4][2];
  for (int off = 32; off; off >>= 1){ sum += __shfl_down(sum, off); sq += __shfl_down(sq, off); }
  int wid = threadIdx.x >> 6;
  if ((threadIdx.x & 63) == 0){ red[wid][0] = sum; red[wid][1] = sq; }
  __syncthreads();
  if (threadIdx.x == 0){
    float s = 0.f, q = 0.f;
    for (int i = 0; i < 4; ++i){ s += red[i][0]; q += red[i][1]; }
    atomicAdd(&st[ST_Y2S + d], s);
    atomicAdd(&st[ST_Y2Q + d], q);
  }
}

// ---------------- K4: covariance + Q/K/V congruence (patch-split LDS, float4 dots) ------
__global__ __launch_bounds__(256) void k4_cov_qkv(const float* __restrict__ y2, const float* __restrict__ st,
    const float* __restrict__ g2, const float* __restrict__ Wq, const float* __restrict__ Wk,
    const float* __restrict__ Wv, float* __restrict__ qkv){
  __shared__ __align__(16) float ysp[3][20][148];  // patch-split, zero-padded to 148
  __shared__ float a2s[20];
  __shared__ __align__(16) float Bt[3][18][20];    // [wt][i][d] = a2[d]*W[d][i]
  __shared__ __align__(16) float G3[3][400];
  __shared__ __align__(16) float Tmt[3][360];      // [m][jj*20+p]
  __shared__ float musum3[3][20];
  __shared__ float rtr3[3];
  int tid = threadIdx.x, n = blockIdx.x;
  if (tid < 20){
    const float invN = 1.f/(2048.f*439.f);
    float s = st[ST_Y2S + tid]*invN;
    float q = st[ST_Y2Q + tid]*invN;
    a2s[tid] = g2[tid] * rsqrtf(q - s*s + 1e-5f);
  }
  const float* yb = y2 + (size_t)n*8780;
  for (int i = tid; i < 8780; i += 256){
    int d = i/439, w = i - d*439;
    int m = (w >= 293) ? 2 : ((w >= 147) ? 1 : 0);
    int lw = w - ((m == 2) ? 293 : ((m == 1) ? 147 : 0));
    ysp[m][d][lw] = yb[i];
  }
  if (tid < 100){   // zero the pad slots
    int d = tid/5, k = tid - d*5;
    int m = (k == 0) ? 0 : ((k < 3) ? 1 : 2);
    int lw = (k == 0) ? 147 : ((k == 1 || k == 3) ? 146 : 147);
    ysp[m][d][lw] = 0.f;
  }
  __syncthreads();
  for (int i = tid; i < 1140; i += 256){
    if (i < 1080){
      int wt = i/360, r = i - wt*360; int d = r/18, jj = r - d*18;
      const float* Wm = (wt==0) ? Wq : ((wt==1) ? Wk : Wv);
      Bt[wt][jj][d] = a2s[d]*Wm[d*18 + jj];
    } else {
      int t = i - 1080; int m = t/20, d = t - m*20;
      const float4* r = (const float4*)&ysp[m][d][0];
      float4 acc = {0.f,0.f,0.f,0.f};
      #pragma unroll 1
      for (int w = 0; w < 37; ++w){ float4 v = r[w]; acc.x+=v.x; acc.y+=v.y; acc.z+=v.z; acc.w+=v.w; }
      musum3[m][d] = acc.x+acc.y+acc.z+acc.w;
    }
  }
  __syncthreads();
  for (int it = tid; it < 630; it += 256){
    int m = it/210, t = it - m*210;
    int rem = t, c = 0;
    while (rem >= 20 - c){ rem -= 20 - c; ++c; }
    int d = c + rem;
    const float4* ra = (const float4*)&ysp[m][c][0];
    const float4* rb = (const float4*)&ysp[m][d][0];
    float4 acc4 = {0.f,0.f,0.f,0.f};
    #pragma unroll 1
    for (int w = 0; w < 37; ++w){
      float4 a = ra[w], b = rb[w];
      acc4.x = fmaf(a.x,b.x,acc4.x); acc4.y = fmaf(a.y,b.y,acc4.y);
      acc4.z = fmaf(a.z,b.z,acc4.z); acc4.w = fmaf(a.w,b.w,acc4.w);
    }
    float invL = (m == 0) ? (1.f/147.f) : (1.f/146.f);
    float acc = (acc4.x+acc4.y+acc4.z+acc4.w) - musum3[m][c]*musum3[m][d]*invL;
    G3[m][c*20 + d] = acc; G3[m][d*20 + c] = acc;
  }
  __syncthreads();
  for (int wt = 0; wt < 3; ++wt){
    for (int i = tid; i < 1083; i += 256){
      if (i < 1080){
        int m = i/360, r = i - m*360; int p = r/18, jj = r - p*18;
        const float4* gr = (const float4*)&G3[m][p*20];
        const float4* br = (const float4*)&Bt[wt][jj][0];
        float4 a4 = {0.f,0.f,0.f,0.f};
        #pragma unroll
        for (int w = 0; w < 5; ++w){
          float4 a = gr[w], b = br[w];
          a4.x = fmaf(a.x,b.x,a4.x); a4.y = fmaf(a.y,b.y,a4.y);
          a4.z = fmaf(a.z,b.z,a4.z); a4.w = fmaf(a.w,b.w,a4.w);
        }
        Tmt[m][jj*20 + p] = a4.x+a4.y+a4.z+a4.w;
      } else if (wt == 0){
        int m = i - 1080;
        float tr = 0.f;
        for (int c = 0; c < 20; ++c){ float a = a2s[c]; tr = fmaf(a*a, G3[m][c*21], tr); }
        rtr3[m] = 1.f/tr;
      }
    }
    __syncthreads();
    for (int it = tid; it < 513; it += 256){
      int m = it/171, t = it - m*171;
      int rem = t, i = 0;
      while (rem >= 18 - i){ rem -= 18 - i; ++i; }
      int jj = i + rem;
      const float4* br = (const float4*)&Bt[wt][i][0];
      const float4* tr = (const float4*)&Tmt[m][jj*20];
      float4 a4 = {0.f,0.f,0.f,0.f};
      #pragma unroll
      for (int w = 0; w < 5; ++w){
        float4 a = br[w], b = tr[w];
        a4.x = fmaf(a.x,b.x,a4.x); a4.y = fmaf(a.y,b.y,a4.y);
        a4.z = fmaf(a.z,b.z,a4.z); a4.w = fmaf(a.w,b.w,a4.w);
      }
      float acc = (a4.x+a4.y+a4.z+a4.w) * rtr3[m];
      if (i == jj) acc += 1e-5f;
      float* outm = qkv + ((size_t)wt*6144 + (size_t)n*3 + m)*324;
      outm[i*18 + jj] = acc; outm[jj*18 + i] = acc;
    }
    __syncthreads();
  }
}

// ---------------- K5: batched 18x18 one-sided (Hestenes) Jacobi ----------------
// B = A (PSD; mode 1 input pre-shifted by SHIFT*I). Rotations orthogonalize
// columns; at convergence b_i = lam_i * u_i, lam_i = ||b_i||. No eigenvector
// accumulation -> 19 DS ops/round (was 38 two-sided). gamma and (c,s) are
// computed bitwise-identically on both partner lanes (same products, same
// summation order; norms exchanged). Valid for PSD only (A^2 aliases +/-lam).
// mode 0: dst = U log(S) U^T. mode 1: fused triu-GEMV with Wl/bl into outp.
__global__ __launch_bounds__(256, 4) void k5_oneside(const float* __restrict__ src, float* __restrict__ dst,
    int nmat, int mode, const float* __restrict__ Wl, const float* __restrict__ bl,
    float* __restrict__ outp){
  __shared__ __align__(16) float stage[12][384];
  __shared__ __align__(16) float wls[2052];
  __shared__ float outacc[4][4];
  int tid = threadIdx.x;
  int wave = tid >> 6, lane = tid & 63;
  int g = (lane >= 54) ? 3 : (lane >= 36 ? 2 : (lane >= 18 ? 1 : 0));
  int j = lane - g*18;
  int gb = g*18;
  int slot = wave*3 + ((g < 3) ? g : 0);
  int mat = blockIdx.x*12 + wave*3 + g;
  bool act = (g < 3) && (mat < nmat);

  if (mode == 1){
    for (int i = tid; i < 2052; i += 256) wls[i] = Wl[i];
    if (tid < 16) outacc[tid >> 2][tid & 3] = 0.f;
  }

  float b[18];
  float sh = (mode == 1) ? SHIFT : 0.f;
  if (act){
    const float* s = src + (size_t)mat*324 + j*18;
    #pragma unroll
    for (int i = 0; i < 18; ++i) b[i] = s[i] + ((i == j) ? sh : 0.f);
  } else {
    #pragma unroll
    for (int i = 0; i < 18; ++i) b[i] = (i == j) ? 1.f : 0.f;
  }
  float nrm;
  { float n0 = 0.f, n1 = 0.f;
    #pragma unroll
    for (int k = 0; k < 18; k += 2){ n0 = fmaf(b[k],b[k],n0); n1 = fmaf(b[k+1],b[k+1],n1); }
    nrm = n0 + n1; }

  #pragma unroll 1
  for (int sweep = 0; sweep < NSWEEP; ++sweep){
    #pragma unroll
    for (int r = 0; r < 17; ++r){
      int xx = j - 1 - r; if (xx < 0) xx += 17;
      int v = r + 17 - xx; if (v >= 17) v -= 17;
      int m = (j == 0) ? (1 + r) : ((xx == 0) ? 0 : (1 + v));
      bool isp = (j == 0) ? true : ((xx == 0) ? false : (xx <= 8));
      int plane = (gb + m) & 63;
      float rv[18];
      #pragma unroll
      for (int k = 0; k < 18; ++k) rv[k] = __shfl(b[k], plane);
      float on = __shfl(nrm, plane);
      float g0 = 0.f, g1 = 0.f;
      #pragma unroll
      for (int k = 0; k < 18; k += 2){ g0 = fmaf(b[k], rv[k], g0); g1 = fmaf(b[k+1], rv[k+1], g1); }
      float gam = g0 + g1;                        // bitwise equal on both lanes
      float alpha = isp ? nrm : on;               // p's norm on both lanes
      float beta  = isp ? on  : nrm;              // q's norm on both lanes
      float tau = (beta - alpha) * 0.5f * __builtin_amdgcn_rcpf(gam);
      float tt = __builtin_amdgcn_rcpf(fabsf(tau) + sqrtf(fmaf(tau, tau, 1.f)));
      float t = (tau >= 0.f) ? tt : -tt;
      if (!(fabsf(gam) > 1e-36f)) t = 0.f;
      float c = __builtin_amdgcn_rsqf(fmaf(t, t, 1.f));
      float s = t*c;
      nrm = fmaf(isp ? -t : t, gam, nrm);         // alpha' = a - t*g ; beta' = b + t*g
      float sg = isp ? -s : s;
      #pragma unroll
      for (int k = 0; k < 18; ++k) b[k] = fmaf(c, b[k], sg*rv[k]);
    }
  }
  // fresh norm -> lambda, f(lambda), weight w = f/lam^2
  float n0 = 0.f, n1 = 0.f;
  #pragma unroll
  for (int k = 0; k < 18; k += 2){ n0 = fmaf(b[k],b[k],n0); n1 = fmaf(b[k+1],b[k+1],n1); }
  float nf = fmaxf(n0 + n1, 1e-30f);
  float fv = (mode == 0) ? (0.5f * logf(nf)) : fmaxf(sqrtf(nf) - SHIFT, LOGEPS);
  float wv = fv * __builtin_amdgcn_rcpf(nf);
  // stage: spT[k*20 + j] = B[k][j] (row-major), w at 360+j
  float* sp = &stage[slot][0];
  if (act){
    #pragma unroll
    for (int k = 0; k < 18; ++k) sp[k*20 + j] = b[k];
    sp[360 + j] = wv;
  }
  __syncthreads();
  if (act){
    float wr[18];
    #pragma unroll
    for (int i = 0; i < 18; ++i) wr[i] = sp[j*20 + i] * sp[360 + i];
    float frow[18];
    #pragma unroll
    for (int i2 = 0; i2 < 18; ++i2){
      const float* br = &sp[i2*20];   // row i2 of B: broadcast across lanes
      float a0 = 0.f;
      #pragma unroll
      for (int k = 0; k < 16; k += 4){
        float4 v4 = *(const float4*)&br[k];
        a0 = fmaf(wr[k],   v4.x, a0); a0 = fmaf(wr[k+1], v4.y, a0);
        a0 = fmaf(wr[k+2], v4.z, a0); a0 = fmaf(wr[k+3], v4.w, a0);
      }
      a0 = fmaf(wr[16], br[16], a0);
      a0 = fmaf(wr[17], br[17], a0);
      frow[i2] = a0;
    }
    if (mode == 0){
      float* orow = dst + (size_t)mat*324 + j*18;
      #pragma unroll
      for (int i2 = 0; i2 < 18; ++i2) orow[i2] = frow[i2];
    } else {
      // m-patch == g (mat = b*3 + m). triu row j -> Wl rows base..base+17-j
      int base = (g*171 + j*(37 - j)/2 - j)*4;
      float o0=0.f, o1=0.f, o2=0.f, o3=0.f;
      #pragma unroll
      for (int jj = 0; jj < 18; ++jj){
        if (jj >= j){
          const float* w4 = &wls[base + jj*4];
          o0 = fmaf(frow[jj], w4[0], o0);
          o1 = fmaf(frow[jj], w4[1], o1);
          o2 = fmaf(frow[jj], w4[2], o2);
          o3 = fmaf(frow[jj], w4[3], o3);
        }
      }
      atomicAdd(&outacc[wave][0], o0);
      atomicAdd(&outacc[wave][1], o1);
      atomicAdd(&outacc[wave][2], o2);
      atomicAdd(&outacc[wave][3], o3);
    }
  }
  if (mode == 1){
    __syncthreads();
    if (tid < 16){
      int bi = tid >> 2, o = tid & 3;
      outp[(blockIdx.x*4 + bi)*4 + o] = outacc[bi][o] + bl[o];
    }
  }
}

// ---------------- K6: energies -> scores -> softmax -> mixed (shuffle-reduced) --------
__global__ __launch_bounds__(128) void k6_attnmix(const float* __restrict__ logs, float* __restrict__ mixed){
  __shared__ float lq[972], lk[972], lv[972];
  __shared__ float ew[2][9];
  __shared__ float P[9];
  int b = blockIdx.x, tid = threadIdx.x;
  const float* q  = logs + (size_t)b*972;
  const float* k_ = logs + 1990656 + (size_t)b*972;
  const float* v_ = logs + 3981312 + (size_t)b*972;
  for (int i = tid; i < 972; i += 128){ lq[i] = q[i]; lk[i] = k_[i]; lv[i] = v_[i]; }
  __syncthreads();
  float e[9] = {0.f,0.f,0.f,0.f,0.f,0.f,0.f,0.f,0.f};
  for (int x = tid; x < 324; x += 128){
    float q0 = lq[x], q1 = lq[324+x], q2 = lq[648+x];
    float k0 = lk[x], k1 = lk[324+x], k2 = lk[648+x];
    float d;
    d = q0-k0; e[0] = fmaf(d,d,e[0]);
    d = q0-k1; e[1] = fmaf(d,d,e[1]);
    d = q0-k2; e[2] = fmaf(d,d,e[2]);
    d = q1-k0; e[3] = fmaf(d,d,e[3]);
    d = q1-k1; e[4] = fmaf(d,d,e[4]);
    d = q1-k2; e[5] = fmaf(d,d,e[5]);
    d = q2-k0; e[6] = fmaf(d,d,e[6]);
    d = q2-k1; e[7] = fmaf(d,d,e[7]);
    d = q2-k2; e[8] = fmaf(d,d,e[8]);
  }
  #pragma unroll
  for (int p = 0; p < 9; ++p)
    for (int off = 32; off; off >>= 1) e[p] += __shfl_down(e[p], off);
  if ((tid & 63) == 0){
    #pragma unroll
    for (int p = 0; p < 9; ++p) ew[tid >> 6][p] = e[p];
  }
  __syncthreads();
  if (tid < 3){
    float en0 = ew[0][tid*3+0] + ew[1][tid*3+0];
    float en1 = ew[0][tid*3+1] + ew[1][tid*3+1];
    float en2 = ew[0][tid*3+2] + ew[1][tid*3+2];
    float s0 = 1.f/(1.f + log1pf(en0));
    float s1 = 1.f/(1.f + log1pf(en1));
    float s2 = 1.f/(1.f + log1pf(en2));
    float mx = fmaxf(s0, fmaxf(s1, s2));
    float e0 = expf(s0-mx), e1 = expf(s1-mx), e2 = expf(s2-mx);
    float inv = 1.f/(e0+e1+e2);
    P[tid*3+0] = e0*inv; P[tid*3+1] = e1*inv; P[tid*3+2] = e2*inv;
  }
  __syncthreads();
  float p00=P[0],p01=P[1],p02=P[2],p10=P[3],p11=P[4],p12=P[5],p20=P[6],p21=P[7],p22=P[8];
  float* mb = mixed + (size_t)b*972;
  for (int x = tid; x < 324; x += 128){
    float v0 = lv[x], v1 = lv[324+x], v2 = lv[648+x];
    mb[x]     = p00*v0 + p01*v1 + p02*v2;
    mb[324+x] = p10*v0 + p11*v1 + p12*v2;
    mb[648+x] = p20*v0 + p21*v1 + p22*v2;
  }
}

// ---------------- launcher ----------------
extern "C" void kernel_launch(void* const* d_in, const int* in_sizes, int n_in,
                              void* d_out, int out_size, void* d_ws, size_t ws_size,
                              hipStream_t stream){
  (void)in_sizes; (void)n_in; (void)out_size; (void)ws_size;
  const float* x   = (const float*)d_in[0];
  const float* W1  = (const float*)d_in[1];
  const float* g1  = (const float*)d_in[3];
  const float* be1 = (const float*)d_in[4];
  const float* W2  = (const float*)d_in[5];
  const float* g2  = (const float*)d_in[7];
  const float* Wq  = (const float*)d_in[9];
  const float* Wk  = (const float*)d_in[10];
  const float* Wv  = (const float*)d_in[11];
  const float* Wl  = (const float*)d_in[12];
  const float* bl  = (const float*)d_in[13];
  float* ws    = (float*)d_ws;
  float* y2    = ws + OFF_Y2;
  float* qkv   = ws + OFF_QKV;
  float* logs  = ws + OFF_Y2;    // overlay: y2 dead after k4
  float* mixed = ws + OFF_QKV;   // overlay: qkv dead after k5#1
  float* st    = ws + OFF_ST;
  float* outp  = (float*)d_out;

  k0_zero    <<<dim3(1),      dim3(256), 0, stream>>>(st);
  k1_xstats  <<<dim3(2048),   dim3(256), 0, stream>>>(x, st);
  k1b_fold   <<<dim3(1),      dim3(64),  0, stream>>>(W1, g1, be1, st);
  k3_conv    <<<dim3(2048),   dim3(512), 0, stream>>>(x, W2, st, y2);
  k3b_y2stats<<<dim3(20,16),  dim3(256), 0, stream>>>(y2, st);
  k4_cov_qkv <<<dim3(2048),   dim3(256), 0, stream>>>(y2, st, g2, Wq, Wk, Wv, qkv);
  k5_oneside <<<dim3(1536),   dim3(256), 0, stream>>>(qkv, logs, 18432, 0, nullptr, nullptr, nullptr);
  k6_attnmix <<<dim3(2048),   dim3(128), 0, stream>>>(logs, mixed);
  k5_oneside <<<dim3(512),    dim3(256), 0, stream>>>(mixed, nullptr, 6144, 1, Wl, bl, outp);
}

// Round 8
// 749.141 us; speedup vs baseline: 1.3954x; 1.0004x over previous
//
#include <hip/hip_runtime.h>
#include <math.h>

// ---------------- workspace layout (floats) ----------------
#define OFF_Y2   0
#define OFF_QKV  17981440
#define OFF_ST   (17981440 + 5971968)
// stats offsets
#define ST_SX   0
#define ST_SXX  22
#define ST_WF   506
#define ST_BF   990
#define ST_Y2S  1012
#define ST_Y2Q  1032
#define ST_TOT  1052

#define LOGEPS -9.210340371976182f
#define NSWEEP 5   // 4 sweeps FAILED: absmax 2.29e-2 > 1.91e-2 thr (r7). 5 -> 3.9e-3.
#define SHIFT  12.0f   // mixed eigenvalues in [-11.62, ~1e-4] -> shifted PSD

// ---------------- K0: zero stats ----------------
__global__ __launch_bounds__(256) void k0_zero(float* __restrict__ st){
  for (int i = threadIdx.x; i < ST_TOT; i += 256) st[i] = 0.f;
}

// ---------------- K1: x second moments (for closed-form BN1 stats) ----------------
__global__ __launch_bounds__(256) void k1_xstats(const float* __restrict__ x, float* __restrict__ st){
  __shared__ __align__(16) float xs[22*444];
  const float* xb = x + (size_t)blockIdx.x * (22*438);
  for (int i = threadIdx.x; i < 22*444; i += 256){
    int h = i / 444, w = i - h*444;
    xs[i] = (w < 438) ? xb[h*438 + w] : 0.f;
  }
  __syncthreads();
  for (int t = threadIdx.x; t < 275; t += 256){
    if (t < 22){
      const float4* r = (const float4*)&xs[t*444];
      float4 acc = {0.f,0.f,0.f,0.f};
      for (int w = 0; w < 111; ++w){ float4 v = r[w]; acc.x+=v.x; acc.y+=v.y; acc.z+=v.z; acc.w+=v.w; }
      atomicAdd(&st[ST_SX + t], acc.x+acc.y+acc.z+acc.w);
    } else {
      int rem = t - 22, h = 0;
      while (rem >= 22 - h){ rem -= 22 - h; ++h; }
      int h2 = h + rem;
      const float4* ra = (const float4*)&xs[h*444];
      const float4* rb = (const float4*)&xs[h2*444];
      float4 acc = {0.f,0.f,0.f,0.f};
      for (int w = 0; w < 111; ++w){
        float4 a = ra[w], b = rb[w];
        acc.x = fmaf(a.x,b.x,acc.x); acc.y = fmaf(a.y,b.y,acc.y);
        acc.z = fmaf(a.z,b.z,acc.z); acc.w = fmaf(a.w,b.w,acc.w);
      }
      atomicAdd(&st[ST_SXX + h*22 + h2], acc.x+acc.y+acc.z+acc.w);
    }
  }
}

// ---------------- K1b: fold BN1 into conv1 weights ----------------
__global__ __launch_bounds__(64) void k1b_fold(const float* __restrict__ W1, const float* __restrict__ g1,
                                               const float* __restrict__ be1, float* __restrict__ st){
  int c = threadIdx.x;
  if (c >= 22) return;
  const float invN = 1.f / (2048.f*438.f);
  float mcol[22];
  float mu0 = 0.f;
  for (int h = 0; h < 22; ++h){ mcol[h] = W1[c*22 + h]; mu0 = fmaf(mcol[h], st[ST_SX + h], mu0); }
  mu0 *= invN;
  float qf = 0.f;
  for (int h = 0; h < 22; ++h)
    for (int h2 = h; h2 < 22; ++h2){
      float w = mcol[h]*mcol[h2]*st[ST_SXX + h*22 + h2];
      qf += (h2 == h) ? w : 2.f*w;
    }
  qf *= invN;
  float var = qf - mu0*mu0;
  float a1 = g1[c] * rsqrtf(var + 1e-5f);
  for (int h = 0; h < 22; ++h) st[ST_WF + h*22 + c] = a1 * mcol[h];
  st[ST_BF + c] = be1[c] - a1 * mu0;   // b1 cancels exactly
}

// ---------------- K3: fused conv1+BN1+conv2 + y2 stats ----------------
// grid (2048, 2): blockIdx.y picks d-half (10 of 20 output channels).
// LDS 52.8 KB -> 3 blocks/CU. conv1 recomputed per half (float2-ized, cheap).
// d-fast conv2 lane mapping keeps zw reads broadcast. Per-channel sum/sumsq
// folded in via LDS + global atomics (replaces k3b). st is written -> non-const.
__global__ __launch_bounds__(256, 3) void k3_conv(const float* __restrict__ x, const float* __restrict__ W2,
                                                  float* __restrict__ st, float* __restrict__ y2){
  __shared__ __align__(16) float zs[22*452 + 20];  // 39.9 KB (+20 OOB slack)
  __shared__ __align__(16) float w2s[10*268];      // 10.7 KB
  __shared__ __align__(16) float wfs[22*24];       // 2.1 KB
  __shared__ float bfs[22];
  __shared__ float sloc[10], qloc[10];
  int tid = threadIdx.x;
  int n = blockIdx.x;
  int dbase = blockIdx.y * 10;
  for (int i = tid; i < 484; i += 256){ int h = i/22, c = i - h*22; wfs[h*24 + c] = st[ST_WF + i]; }
  for (int i = tid; i < 2640; i += 256){ int dl = i/264, r = i - dl*264; w2s[dl*268 + r] = W2[(dbase + dl)*264 + r]; }
  if (tid < 22) bfs[tid] = st[ST_BF + tid];
  if (tid < 10){ sloc[tid] = 0.f; qloc[tid] = 0.f; }
  for (int i = tid; i < 22*14; i += 256){ int c = i/14, k = i - c*14; int w = (k < 6) ? k : (438 + k); zs[c*452 + w] = 0.f; }
  __syncthreads();
  // conv1: 219 threads x 2 columns (float2)
  if (tid < 219){
    float2 acc[22];
    #pragma unroll
    for (int c = 0; c < 22; ++c){ float b = bfs[c]; acc[c].x = b; acc[c].y = b; }
    const float* xb = x + (size_t)n*(22*438) + 2*tid;
    #pragma unroll 1
    for (int h = 0; h < 22; ++h){
      float2 xv = *(const float2*)&xb[h*438];
      #pragma unroll
      for (int c = 0; c < 22; ++c){
        float w = wfs[h*24 + c];
        acc[c].x = fmaf(w, xv.x, acc[c].x);
        acc[c].y = fmaf(w, xv.y, acc[c].y);
      }
    }
    #pragma unroll
    for (int c = 0; c < 22; ++c) *(float2*)&zs[c*452 + 6 + 2*tid] = acc[c];
  }
  __syncthreads();
  // conv2: 190 threads = 19 chunks x 10 d, d-fast
  if (tid < 190){
    int chunk = tid / 10, dl = tid - chunk*10;
    int d = dbase + dl;
    int w0 = chunk*24;
    float acc[24];
    #pragma unroll
    for (int jj = 0; jj < 24; ++jj) acc[jj] = 0.f;
    #pragma unroll 1
    for (int c = 0; c < 22; ++c){
      const float* zr = &zs[c*452 + w0];
      float zw[36];
      #pragma unroll
      for (int k = 0; k < 36; k += 4){ float4 v = *(const float4*)&zr[k]; zw[k]=v.x; zw[k+1]=v.y; zw[k+2]=v.z; zw[k+3]=v.w; }
      const float* wr = &w2s[dl*268 + c*12];
      float wt[12];
      #pragma unroll
      for (int t = 0; t < 12; t += 4){ float4 v = *(const float4*)&wr[t]; wt[t]=v.x; wt[t+1]=v.y; wt[t+2]=v.z; wt[t+3]=v.w; }
      #pragma unroll
      for (int jj = 0; jj < 24; ++jj)
        #pragma unroll
        for (int t = 0; t < 12; ++t)
          acc[jj] = fmaf(wt[t], zw[jj+t], acc[jj]);
    }
    float* yb = y2 + (size_t)n*8780 + d*439;
    float s = 0.f, q = 0.f;
    #pragma unroll
    for (int jj = 0; jj < 24; ++jj){
      int w = w0 + jj;
      if (w < 439){ yb[w] = acc[jj]; s += acc[jj]; q = fmaf(acc[jj], acc[jj], q); }
    }
    atomicAdd(&sloc[dl], s);
    atomicAdd(&qloc[dl], q);
  }
  __syncthreads();
  if (tid < 10){
    atomicAdd(&st[ST_Y2S + dbase + tid], sloc[tid]);
    atomicAdd(&st[ST_Y2Q + dbase + tid], qloc[tid]);
  }
}

// ---------------- K4: covariance + Q/K/V congruence (patch-split LDS, float4 dots) ------
__global__ __launch_bounds__(256) void k4_cov_qkv(const float* __restrict__ y2, const float* __restrict__ st,
    const float* __restrict__ g2, const float* __restrict__ Wq, const float* __restrict__ Wk,
    const float* __restrict__ Wv, float* __restrict__ qkv){
  __shared__ __align__(16) float ysp[3][20][148];  // patch-split, zero-padded to 148
  __shared__ float a2s[20];
  __shared__ __align__(16) float Bt[3][18][20];    // [wt][i][d] = a2[d]*W[d][i]
  __shared__ __align__(16) float G3[3][400];
  __shared__ __align__(16) float Tmt[3][360];      // [m][jj*20+p]
  __shared__ float musum3[3][20];
  __shared__ float rtr3[3];
  int tid = threadIdx.x, n = blockIdx.x;
  if (tid < 20){
    const float invN = 1.f/(2048.f*439.f);
    float s = st[ST_Y2S + tid]*invN;
    float q = st[ST_Y2Q + tid]*invN;
    a2s[tid] = g2[tid] * rsqrtf(q - s*s + 1e-5f);
  }
  const float* yb = y2 + (size_t)n*8780;
  for (int i = tid; i < 8780; i += 256){
    int d = i/439, w = i - d*439;
    int m = (w >= 293) ? 2 : ((w >= 147) ? 1 : 0);
    int lw = w - ((m == 2) ? 293 : ((m == 1) ? 147 : 0));
    ysp[m][d][lw] = yb[i];
  }
  if (tid < 100){   // zero the pad slots
    int d = tid/5, k = tid - d*5;
    int m = (k == 0) ? 0 : ((k < 3) ? 1 : 2);
    int lw = (k == 0) ? 147 : ((k == 1 || k == 3) ? 146 : 147);
    ysp[m][d][lw] = 0.f;
  }
  __syncthreads();
  for (int i = tid; i < 1140; i += 256){
    if (i < 1080){
      int wt = i/360, r = i - wt*360; int d = r/18, jj = r - d*18;
      const float* Wm = (wt==0) ? Wq : ((wt==1) ? Wk : Wv);
      Bt[wt][jj][d] = a2s[d]*Wm[d*18 + jj];
    } else {
      int t = i - 1080; int m = t/20, d = t - m*20;
      const float4* r = (const float4*)&ysp[m][d][0];
      float4 acc = {0.f,0.f,0.f,0.f};
      #pragma unroll 1
      for (int w = 0; w < 37; ++w){ float4 v = r[w]; acc.x+=v.x; acc.y+=v.y; acc.z+=v.z; acc.w+=v.w; }
      musum3[m][d] = acc.x+acc.y+acc.z+acc.w;
    }
  }
  __syncthreads();
  for (int it = tid; it < 630; it += 256){
    int m = it/210, t = it - m*210;
    int rem = t, c = 0;
    while (rem >= 20 - c){ rem -= 20 - c; ++c; }
    int d = c + rem;
    const float4* ra = (const float4*)&ysp[m][c][0];
    const float4* rb = (const float4*)&ysp[m][d][0];
    float4 acc4 = {0.f,0.f,0.f,0.f};
    #pragma unroll 1
    for (int w = 0; w < 37; ++w){
      float4 a = ra[w], b = rb[w];
      acc4.x = fmaf(a.x,b.x,acc4.x); acc4.y = fmaf(a.y,b.y,acc4.y);
      acc4.z = fmaf(a.z,b.z,acc4.z); acc4.w = fmaf(a.w,b.w,acc4.w);
    }
    float invL = (m == 0) ? (1.f/147.f) : (1.f/146.f);
    float acc = (acc4.x+acc4.y+acc4.z+acc4.w) - musum3[m][c]*musum3[m][d]*invL;
    G3[m][c*20 + d] = acc; G3[m][d*20 + c] = acc;
  }
  __syncthreads();
  for (int wt = 0; wt < 3; ++wt){
    for (int i = tid; i < 1083; i += 256){
      if (i < 1080){
        int m = i/360, r = i - m*360; int p = r/18, jj = r - p*18;
        const float4* gr = (const float4*)&G3[m][p*20];
        const float4* br = (const float4*)&Bt[wt][jj][0];
        float4 a4 = {0.f,0.f,0.f,0.f};
        #pragma unroll
        for (int w = 0; w < 5; ++w){
          float4 a = gr[w], b = br[w];
          a4.x = fmaf(a.x,b.x,a4.x); a4.y = fmaf(a.y,b.y,a4.y);
          a4.z = fmaf(a.z,b.z,a4.z); a4.w = fmaf(a.w,b.w,a4.w);
        }
        Tmt[m][jj*20 + p] = a4.x+a4.y+a4.z+a4.w;
      } else if (wt == 0){
        int m = i - 1080;
        float tr = 0.f;
        for (int c = 0; c < 20; ++c){ float a = a2s[c]; tr = fmaf(a*a, G3[m][c*21], tr); }
        rtr3[m] = 1.f/tr;
      }
    }
    __syncthreads();
    for (int it = tid; it < 513; it += 256){
      int m = it/171, t = it - m*171;
      int rem = t, i = 0;
      while (rem >= 18 - i){ rem -= 18 - i; ++i; }
      int jj = i + rem;
      const float4* br = (const float4*)&Bt[wt][i][0];
      const float4* tr = (const float4*)&Tmt[m][jj*20];
      float4 a4 = {0.f,0.f,0.f,0.f};
      #pragma unroll
      for (int w = 0; w < 5; ++w){
        float4 a = br[w], b = tr[w];
        a4.x = fmaf(a.x,b.x,a4.x); a4.y = fmaf(a.y,b.y,a4.y);
        a4.z = fmaf(a.z,b.z,a4.z); a4.w = fmaf(a.w,b.w,a4.w);
      }
      float acc = (a4.x+a4.y+a4.z+a4.w) * rtr3[m];
      if (i == jj) acc += 1e-5f;
      float* outm = qkv + ((size_t)wt*6144 + (size_t)n*3 + m)*324;
      outm[i*18 + jj] = acc; outm[jj*18 + i] = acc;
    }
    __syncthreads();
  }
}

// ---------------- K5: batched 18x18 one-sided (Hestenes) Jacobi ----------------
// B = A (PSD; mode 1 input pre-shifted by SHIFT*I). Columns orthogonalize;
// b_i -> lam_i*u_i. 19 DS ops/round. (c,s) bitwise-identical on both partner
// lanes. mode 0: dst = U log(S) U^T. mode 1: fused triu-GEMV -> outp.
__global__ __launch_bounds__(256, 4) void k5_oneside(const float* __restrict__ src, float* __restrict__ dst,
    int nmat, int mode, const float* __restrict__ Wl, const float* __restrict__ bl,
    float* __restrict__ outp){
  __shared__ __align__(16) float stage[12][384];
  __shared__ __align__(16) float wls[2052];
  __shared__ float outacc[4][4];
  int tid = threadIdx.x;
  int wave = tid >> 6, lane = tid & 63;
  int g = (lane >= 54) ? 3 : (lane >= 36 ? 2 : (lane >= 18 ? 1 : 0));
  int j = lane - g*18;
  int gb = g*18;
  int slot = wave*3 + ((g < 3) ? g : 0);
  int mat = blockIdx.x*12 + wave*3 + g;
  bool act = (g < 3) && (mat < nmat);

  if (mode == 1){
    for (int i = tid; i < 2052; i += 256) wls[i] = Wl[i];
    if (tid < 16) outacc[tid >> 2][tid & 3] = 0.f;
  }

  float b[18];
  float sh = (mode == 1) ? SHIFT : 0.f;
  if (act){
    const float* s = src + (size_t)mat*324 + j*18;
    #pragma unroll
    for (int i = 0; i < 18; ++i) b[i] = s[i] + ((i == j) ? sh : 0.f);
  } else {
    #pragma unroll
    for (int i = 0; i < 18; ++i) b[i] = (i == j) ? 1.f : 0.f;
  }
  float nrm;
  { float n0 = 0.f, n1 = 0.f;
    #pragma unroll
    for (int k = 0; k < 18; k += 2){ n0 = fmaf(b[k],b[k],n0); n1 = fmaf(b[k+1],b[k+1],n1); }
    nrm = n0 + n1; }

  #pragma unroll 1
  for (int sweep = 0; sweep < NSWEEP; ++sweep){
    #pragma unroll
    for (int r = 0; r < 17; ++r){
      int xx = j - 1 - r; if (xx < 0) xx += 17;
      int v = r + 17 - xx; if (v >= 17) v -= 17;
      int m = (j == 0) ? (1 + r) : ((xx == 0) ? 0 : (1 + v));
      bool isp = (j == 0) ? true : ((xx == 0) ? false : (xx <= 8));
      int plane = (gb + m) & 63;
      float rv[18];
      #pragma unroll
      for (int k = 0; k < 18; ++k) rv[k] = __shfl(b[k], plane);
      float on = __shfl(nrm, plane);
      float g0 = 0.f, g1 = 0.f;
      #pragma unroll
      for (int k = 0; k < 18; k += 2){ g0 = fmaf(b[k], rv[k], g0); g1 = fmaf(b[k+1], rv[k+1], g1); }
      float gam = g0 + g1;                        // bitwise equal on both lanes
      float alpha = isp ? nrm : on;
      float beta  = isp ? on  : nrm;
      float tau = (beta - alpha) * 0.5f * __builtin_amdgcn_rcpf(gam);
      float tt = __builtin_amdgcn_rcpf(fabsf(tau) + sqrtf(fmaf(tau, tau, 1.f)));
      float t = (tau >= 0.f) ? tt : -tt;
      if (!(fabsf(gam) > 1e-36f)) t = 0.f;
      float c = __builtin_amdgcn_rsqf(fmaf(t, t, 1.f));
      float s = t*c;
      nrm = fmaf(isp ? -t : t, gam, nrm);
      float sg = isp ? -s : s;
      #pragma unroll
      for (int k = 0; k < 18; ++k) b[k] = fmaf(c, b[k], sg*rv[k]);
    }
  }
  float n0 = 0.f, n1 = 0.f;
  #pragma unroll
  for (int k = 0; k < 18; k += 2){ n0 = fmaf(b[k],b[k],n0); n1 = fmaf(b[k+1],b[k+1],n1); }
  float nf = fmaxf(n0 + n1, 1e-30f);
  float fv = (mode == 0) ? (0.5f * logf(nf)) : fmaxf(sqrtf(nf) - SHIFT, LOGEPS);
  float wv = fv * __builtin_amdgcn_rcpf(nf);
  float* sp = &stage[slot][0];
  if (act){
    #pragma unroll
    for (int k = 0; k < 18; ++k) sp[k*20 + j] = b[k];
    sp[360 + j] = wv;
  }
  __syncthreads();
  if (act){
    float wr[18];
    #pragma unroll
    for (int i = 0; i < 18; ++i) wr[i] = sp[j*20 + i] * sp[360 + i];
    float frow[18];
    #pragma unroll
    for (int i2 = 0; i2 < 18; ++i2){
      const float* br = &sp[i2*20];
      float a0 = 0.f;
      #pragma unroll
      for (int k = 0; k < 16; k += 4){
        float4 v4 = *(const float4*)&br[k];
        a0 = fmaf(wr[k],   v4.x, a0); a0 = fmaf(wr[k+1], v4.y, a0);
        a0 = fmaf(wr[k+2], v4.z, a0); a0 = fmaf(wr[k+3], v4.w, a0);
      }
      a0 = fmaf(wr[16], br[16], a0);
      a0 = fmaf(wr[17], br[17], a0);
      frow[i2] = a0;
    }
    if (mode == 0){
      float* orow = dst + (size_t)mat*324 + j*18;
      #pragma unroll
      for (int i2 = 0; i2 < 18; ++i2) orow[i2] = frow[i2];
    } else {
      int base = (g*171 + j*(37 - j)/2 - j)*4;
      float o0=0.f, o1=0.f, o2=0.f, o3=0.f;
      #pragma unroll
      for (int jj = 0; jj < 18; ++jj){
        if (jj >= j){
          const float* w4 = &wls[base + jj*4];
          o0 = fmaf(frow[jj], w4[0], o0);
          o1 = fmaf(frow[jj], w4[1], o1);
          o2 = fmaf(frow[jj], w4[2], o2);
          o3 = fmaf(frow[jj], w4[3], o3);
        }
      }
      atomicAdd(&outacc[wave][0], o0);
      atomicAdd(&outacc[wave][1], o1);
      atomicAdd(&outacc[wave][2], o2);
      atomicAdd(&outacc[wave][3], o3);
    }
  }
  if (mode == 1){
    __syncthreads();
    if (tid < 16){
      int bi = tid >> 2, o = tid & 3;
      outp[(blockIdx.x*4 + bi)*4 + o] = outacc[bi][o] + bl[o];
    }
  }
}

// ---------------- K6: energies -> scores -> softmax -> mixed (shuffle-reduced) --------
__global__ __launch_bounds__(128) void k6_attnmix(const float* __restrict__ logs, float* __restrict__ mixed){
  __shared__ float lq[972], lk[972], lv[972];
  __shared__ float ew[2][9];
  __shared__ float P[9];
  int b = blockIdx.x, tid = threadIdx.x;
  const float* q  = logs + (size_t)b*972;
  const float* k_ = logs + 1990656 + (size_t)b*972;
  const float* v_ = logs + 3981312 + (size_t)b*972;
  for (int i = tid; i < 972; i += 128){ lq[i] = q[i]; lk[i] = k_[i]; lv[i] = v_[i]; }
  __syncthreads();
  float e[9] = {0.f,0.f,0.f,0.f,0.f,0.f,0.f,0.f,0.f};
  for (int x = tid; x < 324; x += 128){
    float q0 = lq[x], q1 = lq[324+x], q2 = lq[648+x];
    float k0 = lk[x], k1 = lk[324+x], k2 = lk[648+x];
    float d;
    d = q0-k0; e[0] = fmaf(d,d,e[0]);
    d = q0-k1; e[1] = fmaf(d,d,e[1]);
    d = q0-k2; e[2] = fmaf(d,d,e[2]);
    d = q1-k0; e[3] = fmaf(d,d,e[3]);
    d = q1-k1; e[4] = fmaf(d,d,e[4]);
    d = q1-k2; e[5] = fmaf(d,d,e[5]);
    d = q2-k0; e[6] = fmaf(d,d,e[6]);
    d = q2-k1; e[7] = fmaf(d,d,e[7]);
    d = q2-k2; e[8] = fmaf(d,d,e[8]);
  }
  #pragma unroll
  for (int p = 0; p < 9; ++p)
    for (int off = 32; off; off >>= 1) e[p] += __shfl_down(e[p], off);
  if ((tid & 63) == 0){
    #pragma unroll
    for (int p = 0; p < 9; ++p) ew[tid >> 6][p] = e[p];
  }
  __syncthreads();
  if (tid < 3){
    float en0 = ew[0][tid*3+0] + ew[1][tid*3+0];
    float en1 = ew[0][tid*3+1] + ew[1][tid*3+1];
    float en2 = ew[0][tid*3+2] + ew[1][tid*3+2];
    float s0 = 1.f/(1.f + log1pf(en0));
    float s1 = 1.f/(1.f + log1pf(en1));
    float s2 = 1.f/(1.f + log1pf(en2));
    float mx = fmaxf(s0, fmaxf(s1, s2));
    float e0 = expf(s0-mx), e1 = expf(s1-mx), e2 = expf(s2-mx);
    float inv = 1.f/(e0+e1+e2);
    P[tid*3+0] = e0*inv; P[tid*3+1] = e1*inv; P[tid*3+2] = e2*inv;
  }
  __syncthreads();
  float p00=P[0],p01=P[1],p02=P[2],p10=P[3],p11=P[4],p12=P[5],p20=P[6],p21=P[7],p22=P[8];
  float* mb = mixed + (size_t)b*972;
  for (int x = tid; x < 324; x += 128){
    float v0 = lv[x], v1 = lv[324+x], v2 = lv[648+x];
    mb[x]     = p00*v0 + p01*v1 + p02*v2;
    mb[324+x] = p10*v0 + p11*v1 + p12*v2;
    mb[648+x] = p20*v0 + p21*v1 + p22*v2;
  }
}

// ---------------- launcher ----------------
extern "C" void kernel_launch(void* const* d_in, const int* in_sizes, int n_in,
                              void* d_out, int out_size, void* d_ws, size_t ws_size,
                              hipStream_t stream){
  (void)in_sizes; (void)n_in; (void)out_size; (void)ws_size;
  const float* x   = (const float*)d_in[0];
  const float* W1  = (const float*)d_in[1];
  const float* g1  = (const float*)d_in[3];
  const float* be1 = (const float*)d_in[4];
  const float* W2  = (const float*)d_in[5];
  const float* g2  = (const float*)d_in[7];
  const float* Wq  = (const float*)d_in[9];
  const float* Wk  = (const float*)d_in[10];
  const float* Wv  = (const float*)d_in[11];
  const float* Wl  = (const float*)d_in[12];
  const float* bl  = (const float*)d_in[13];
  float* ws    = (float*)d_ws;
  float* y2    = ws + OFF_Y2;
  float* qkv   = ws + OFF_QKV;
  float* logs  = ws + OFF_Y2;    // overlay: y2 dead after k4
  float* mixed = ws + OFF_QKV;   // overlay: qkv dead after k5#1
  float* st    = ws + OFF_ST;
  float* outp  = (float*)d_out;

  k0_zero    <<<dim3(1),       dim3(256), 0, stream>>>(st);
  k1_xstats  <<<dim3(2048),    dim3(256), 0, stream>>>(x, st);
  k1b_fold   <<<dim3(1),       dim3(64),  0, stream>>>(W1, g1, be1, st);
  k3_conv    <<<dim3(2048,2),  dim3(256), 0, stream>>>(x, W2, st, y2);
  k4_cov_qkv <<<dim3(2048),    dim3(256), 0, stream>>>(y2, st, g2, Wq, Wk, Wv, qkv);
  k5_oneside <<<dim3(1536),    dim3(256), 0, stream>>>(qkv, logs, 18432, 0, nullptr, nullptr, nullptr);
  k6_attnmix <<<dim3(2048),    dim3(128), 0, stream>>>(logs, mixed);
  k5_oneside <<<dim3(512),     dim3(256), 0, stream>>>(mixed, nullptr, 6144, 1, Wl, bl, outp);
}